// Round 1
// baseline (673.343 us; speedup 1.0000x reference)
//
#include <hip/hip_runtime.h>

#define IN_C 512
#define HID  128
#define HID2 64

// ---------------- edge_index dtype detection ----------------
// Reference declares int64 edge_index. If tensors really are int64 (little
// endian, values < 2^31), every odd 32-bit word is 0. If int32, odd words are
// random node ids in [0,50000) -> P(all 256 zero) ~ 0. One block decides.
__global__ void k_detect(const unsigned* __restrict__ ei, int* __restrict__ flag) {
  __shared__ int nz;
  if (threadIdx.x == 0) nz = 0;
  __syncthreads();
  if (ei[2 * threadIdx.x + 1] != 0u) atomicOr(&nz, 1);
  __syncthreads();
  if (threadIdx.x == 0) *flag = (nz == 0) ? 1 : 0;  // 1 => int64
}

__device__ __forceinline__ int edge_at(const unsigned* __restrict__ ei, int f, int i) {
  return (int)(f ? ei[2 * (size_t)i] : ei[i]);
}

// ---------------- degree + in-degree counts ----------------
__global__ void k_deg(const unsigned* __restrict__ ei, const int* __restrict__ flag,
                      const float* __restrict__ ew, float* __restrict__ deg,
                      int* __restrict__ cnt, int E) {
  int f = *flag;
  for (int e = blockIdx.x * blockDim.x + threadIdx.x; e < E; e += gridDim.x * blockDim.x) {
    int c = edge_at(ei, f, E + e);
    atomicAdd(&deg[c], ew[e]);
    atomicAdd(&cnt[c], 1);
  }
}

__global__ void k_dinv(const float* __restrict__ deg, float* __restrict__ dinv, int N) {
  int i = blockIdx.x * blockDim.x + threadIdx.x;
  if (i < N) dinv[i] = rsqrtf(deg[i] + 1.0f);  // +1 = self loop; always > 0
}

// exclusive prefix sum of cnt[N] -> rowptr[N+1]; offs = copy for the fill pass
__global__ __launch_bounds__(1024) void k_scan(const int* __restrict__ cnt,
                                               int* __restrict__ rowptr,
                                               int* __restrict__ offs, int N) {
  __shared__ int sums[1024];
  int t = threadIdx.x;
  int chunk = (N + 1023) >> 10;
  int base = t * chunk;
  int s = 0;
  for (int j = 0; j < chunk; j++) {
    int idx = base + j;
    if (idx < N) s += cnt[idx];
  }
  sums[t] = s;
  __syncthreads();
  for (int d = 1; d < 1024; d <<= 1) {
    int v = (t >= d) ? sums[t - d] : 0;
    __syncthreads();
    sums[t] += v;
    __syncthreads();
  }
  int excl = (t == 0) ? 0 : sums[t - 1];
  for (int j = 0; j < chunk; j++) {
    int idx = base + j;
    if (idx < N) {
      rowptr[idx] = excl;
      offs[idx] = excl;
      excl += cnt[idx];
    }
  }
  if (t == 1023) rowptr[N] = sums[1023];
}

// scatter edges into CSR-by-destination; bake symmetric norm into weight
__global__ void k_fill(const unsigned* __restrict__ ei, const int* __restrict__ flag,
                       const float* __restrict__ ew, const float* __restrict__ dinv,
                       int* __restrict__ offs, int* __restrict__ csrc,
                       float* __restrict__ cw, int E) {
  int f = *flag;
  for (int e = blockIdx.x * blockDim.x + threadIdx.x; e < E; e += gridDim.x * blockDim.x) {
    int r = edge_at(ei, f, e);
    int c = edge_at(ei, f, E + e);
    int p = atomicAdd(&offs[c], 1);
    csrc[p] = r;
    cw[p] = dinv[r] * ew[e] * dinv[c];
  }
}

// ---------------- GEMM1: h = x[M,512] @ W1[128,512]^T ----------------
// 64-row x 128-col block tile, 256 threads, 4x8 per-thread tile, BK=32.
__global__ __launch_bounds__(256) void k_gemm1(const float* __restrict__ x,
                                               const float* __restrict__ W,
                                               float* __restrict__ h, int M) {
  __shared__ float xs[32][68];   // [k][row], stride 68 floats = 272 B (16B-aligned)
  __shared__ float ws[32][132];  // [k][n]
  const int t = threadIdx.x, tx = t & 15, ty = t >> 4;
  const int m0 = blockIdx.x * 64;
  float acc[4][8];
#pragma unroll
  for (int r = 0; r < 4; r++)
#pragma unroll
    for (int c = 0; c < 8; c++) acc[r][c] = 0.f;

  for (int k0 = 0; k0 < IN_C; k0 += 32) {
#pragma unroll
    for (int p = 0; p < 2; p++) {  // x tile: 64 rows x 32 k = 512 float4
      int i = t + p * 256, row = i >> 3, kc = i & 7;
      int gr = m0 + row;
      if (gr >= M) gr = M - 1;
      float4 v = *(const float4*)(x + (size_t)gr * IN_C + k0 + kc * 4);
      xs[kc * 4 + 0][row] = v.x;
      xs[kc * 4 + 1][row] = v.y;
      xs[kc * 4 + 2][row] = v.z;
      xs[kc * 4 + 3][row] = v.w;
    }
#pragma unroll
    for (int p = 0; p < 4; p++) {  // W tile: 128 n x 32 k = 1024 float4
      int i = t + p * 256, n = i >> 3, kc = i & 7;
      float4 v = *(const float4*)(W + (size_t)n * IN_C + k0 + kc * 4);
      ws[kc * 4 + 0][n] = v.x;
      ws[kc * 4 + 1][n] = v.y;
      ws[kc * 4 + 2][n] = v.z;
      ws[kc * 4 + 3][n] = v.w;
    }
    __syncthreads();
#pragma unroll
    for (int kk = 0; kk < 32; kk++) {
      float4 a = *(const float4*)&xs[kk][ty * 4];
      float4 b0 = *(const float4*)&ws[kk][tx * 4];
      float4 b1 = *(const float4*)&ws[kk][tx * 4 + 64];
      float ar[4] = {a.x, a.y, a.z, a.w};
      float br[8] = {b0.x, b0.y, b0.z, b0.w, b1.x, b1.y, b1.z, b1.w};
#pragma unroll
      for (int r = 0; r < 4; r++)
#pragma unroll
        for (int c = 0; c < 8; c++) acc[r][c] += ar[r] * br[c];
    }
    __syncthreads();
  }
#pragma unroll
  for (int r = 0; r < 4; r++) {
    int gr = m0 + ty * 4 + r;
    if (gr < M) {
      float4 o0 = {acc[r][0], acc[r][1], acc[r][2], acc[r][3]};
      float4 o1 = {acc[r][4], acc[r][5], acc[r][6], acc[r][7]};
      *(float4*)(h + (size_t)gr * HID + tx * 4) = o0;
      *(float4*)(h + (size_t)gr * HID + tx * 4 + 64) = o1;
    }
  }
}

// ---------------- GEMM2: h2 = z[M,128] @ W2[64,128]^T ----------------
__global__ __launch_bounds__(256) void k_gemm2(const float* __restrict__ z,
                                               const float* __restrict__ W,
                                               float* __restrict__ h, int M) {
  __shared__ float zs[32][68];
  __shared__ float ws2[32][68];
  const int t = threadIdx.x, tx = t & 15, ty = t >> 4;
  const int m0 = blockIdx.x * 64;
  float acc[4][4];
#pragma unroll
  for (int r = 0; r < 4; r++)
#pragma unroll
    for (int c = 0; c < 4; c++) acc[r][c] = 0.f;

  for (int k0 = 0; k0 < HID; k0 += 32) {
#pragma unroll
    for (int p = 0; p < 2; p++) {  // z tile: 64 rows x 32 k
      int i = t + p * 256, row = i >> 3, kc = i & 7;
      int gr = m0 + row;
      if (gr >= M) gr = M - 1;
      float4 v = *(const float4*)(z + (size_t)gr * HID + k0 + kc * 4);
      zs[kc * 4 + 0][row] = v.x;
      zs[kc * 4 + 1][row] = v.y;
      zs[kc * 4 + 2][row] = v.z;
      zs[kc * 4 + 3][row] = v.w;
    }
#pragma unroll
    for (int p = 0; p < 2; p++) {  // W2 tile: 64 n x 32 k
      int i = t + p * 256, n = i >> 3, kc = i & 7;
      float4 v = *(const float4*)(W + (size_t)n * HID + k0 + kc * 4);
      ws2[kc * 4 + 0][n] = v.x;
      ws2[kc * 4 + 1][n] = v.y;
      ws2[kc * 4 + 2][n] = v.z;
      ws2[kc * 4 + 3][n] = v.w;
    }
    __syncthreads();
#pragma unroll
    for (int kk = 0; kk < 32; kk++) {
      float4 a = *(const float4*)&zs[kk][ty * 4];
      float4 b = *(const float4*)&ws2[kk][tx * 4];
      float ar[4] = {a.x, a.y, a.z, a.w};
      float br[4] = {b.x, b.y, b.z, b.w};
#pragma unroll
      for (int r = 0; r < 4; r++)
#pragma unroll
        for (int c = 0; c < 4; c++) acc[r][c] += ar[r] * br[c];
    }
    __syncthreads();
  }
#pragma unroll
  for (int r = 0; r < 4; r++) {
    int gr = m0 + ty * 4 + r;
    if (gr < M) {
      float4 o = {acc[r][0], acc[r][1], acc[r][2], acc[r][3]};
      *(float4*)(h + (size_t)gr * HID2 + tx * 4) = o;
    }
  }
}

// ---------------- aggregation (pull over CSR) + bias + PReLU ----------------
// one wave per destination node; 64 lanes x float2 = 128 features
__global__ void k_agg1(const float* __restrict__ h, const int* __restrict__ rowptr,
                       const int* __restrict__ csrc, const float* __restrict__ cw,
                       const float* __restrict__ dinv, const float* __restrict__ bias,
                       const float* __restrict__ alpha, float* __restrict__ z, int N) {
  int node = blockIdx.x * 4 + (threadIdx.x >> 6);
  int lane = threadIdx.x & 63;
  if (node >= N) return;
  const float2* hp = (const float2*)h;
  float2 acc = make_float2(0.f, 0.f);
  int s = rowptr[node], epd = rowptr[node + 1];
  for (int e = s; e < epd; e++) {
    int src = csrc[e];
    float wv = cw[e];
    float2 v = hp[(size_t)src * 64 + lane];
    acc.x += wv * v.x;
    acc.y += wv * v.y;
  }
  float di = dinv[node];
  float sw = di * di;  // self-loop norm
  float2 v = hp[(size_t)node * 64 + lane];
  acc.x += sw * v.x;
  acc.y += sw * v.y;
  acc.x += bias[lane * 2];
  acc.y += bias[lane * 2 + 1];
  float a0 = alpha[lane * 2], a1 = alpha[lane * 2 + 1];
  acc.x = acc.x >= 0.f ? acc.x : a0 * acc.x;
  acc.y = acc.y >= 0.f ? acc.y : a1 * acc.y;
  ((float2*)z)[(size_t)node * 64 + lane] = acc;
}

// one wave per node; 64 lanes = 64 features
__global__ void k_agg2(const float* __restrict__ h, const int* __restrict__ rowptr,
                       const int* __restrict__ csrc, const float* __restrict__ cw,
                       const float* __restrict__ dinv, const float* __restrict__ bias,
                       const float* __restrict__ alpha, float* __restrict__ out, int N) {
  int node = blockIdx.x * 4 + (threadIdx.x >> 6);
  int lane = threadIdx.x & 63;
  if (node >= N) return;
  float acc = 0.f;
  int s = rowptr[node], epd = rowptr[node + 1];
  for (int e = s; e < epd; e++) {
    acc += cw[e] * h[(size_t)csrc[e] * HID2 + lane];
  }
  float di = dinv[node];
  acc += di * di * h[(size_t)node * HID2 + lane];
  acc += bias[lane];
  float a = alpha[lane];
  acc = acc >= 0.f ? acc : a * acc;
  out[(size_t)node * HID2 + lane] = acc;
}

extern "C" void kernel_launch(void* const* d_in, const int* in_sizes, int n_in,
                              void* d_out, int out_size, void* d_ws, size_t ws_size,
                              hipStream_t stream) {
  const float* x = (const float*)d_in[0];
  const unsigned* ei = (const unsigned*)d_in[1];
  const float* ew = (const float*)d_in[2];
  const float* W1 = (const float*)d_in[3];
  const float* b1 = (const float*)d_in[4];
  const float* a1 = (const float*)d_in[5];
  const float* W2 = (const float*)d_in[6];
  const float* b2 = (const float*)d_in[7];
  const float* a2 = (const float*)d_in[8];
  float* out = (float*)d_out;

  const int N = in_sizes[0] / IN_C;
  const int E = in_sizes[2];

  char* w = (char*)d_ws;
  auto alloc = [&](size_t bytes) -> void* {
    void* p = (void*)w;
    w += (bytes + 255) / 256 * 256;
    return p;
  };
  int* flag = (int*)alloc(4);
  float* deg = (float*)alloc((size_t)N * 4);
  float* dinv = (float*)alloc((size_t)N * 4);
  int* cnt = (int*)alloc((size_t)N * 4);
  int* rowptr = (int*)alloc((size_t)(N + 1) * 4);
  int* offs = (int*)alloc((size_t)N * 4);
  int* csrc = (int*)alloc((size_t)E * 4);
  float* cw = (float*)alloc((size_t)E * 4);
  float* h1 = (float*)alloc((size_t)N * HID * 4);
  float* z1 = (float*)alloc((size_t)N * HID * 4);
  float* h2 = (float*)alloc((size_t)N * HID2 * 4);

  hipMemsetAsync(deg, 0, (size_t)N * 4, stream);
  hipMemsetAsync(cnt, 0, (size_t)N * 4, stream);

  k_detect<<<1, 256, 0, stream>>>(ei, flag);
  k_deg<<<2048, 256, 0, stream>>>(ei, flag, ew, deg, cnt, E);
  k_dinv<<<(N + 255) / 256, 256, 0, stream>>>(deg, dinv, N);
  k_scan<<<1, 1024, 0, stream>>>(cnt, rowptr, offs, N);
  k_fill<<<2048, 256, 0, stream>>>(ei, flag, ew, dinv, offs, csrc, cw, E);

  k_gemm1<<<(N + 63) / 64, 256, 0, stream>>>(x, W1, h1, N);
  k_agg1<<<(N + 3) / 4, 256, 0, stream>>>(h1, rowptr, csrc, cw, dinv, b1, a1, z1, N);
  k_gemm2<<<(N + 63) / 64, 256, 0, stream>>>(z1, W2, h2, N);
  k_agg2<<<(N + 3) / 4, 256, 0, stream>>>(h2, rowptr, csrc, cw, dinv, b2, a2, out, N);
}

// Round 3
// 562.352 us; speedup vs baseline: 1.1974x; 1.1974x over previous
//
#include <hip/hip_runtime.h>

#define IN_C 512
#define HID  128
#define HID2 64

// ---------------- edge_index dtype detection ----------------
__global__ void k_detect(const unsigned* __restrict__ ei, int* __restrict__ flag) {
  __shared__ int nz;
  if (threadIdx.x == 0) nz = 0;
  __syncthreads();
  if (ei[2 * threadIdx.x + 1] != 0u) atomicOr(&nz, 1);
  __syncthreads();
  if (threadIdx.x == 0) *flag = (nz == 0) ? 1 : 0;  // 1 => int64
}

__device__ __forceinline__ int edge_at(const unsigned* __restrict__ ei, int f, int i) {
  return (int)(f ? ei[2 * (size_t)i] : ei[i]);
}

// ---------------- degree + in-degree counts ----------------
__global__ void k_deg(const unsigned* __restrict__ ei, const int* __restrict__ flag,
                      const float* __restrict__ ew, float* __restrict__ deg,
                      int* __restrict__ cnt, int E) {
  int f = *flag;
  for (int e = blockIdx.x * blockDim.x + threadIdx.x; e < E; e += gridDim.x * blockDim.x) {
    int c = edge_at(ei, f, E + e);
    atomicAdd(&deg[c], ew[e]);
    atomicAdd(&cnt[c], 1);
  }
}

__global__ void k_dinv(const float* __restrict__ deg, float* __restrict__ dinv, int N) {
  int i = blockIdx.x * blockDim.x + threadIdx.x;
  if (i < N) dinv[i] = rsqrtf(deg[i] + 1.0f);  // +1 = self loop; always > 0
}

// ---------------- hierarchical exclusive scan of cnt[N] ----------------
// A: per-block (1024 elems) local exclusive scan -> part[], block sums -> bsum[]
__global__ __launch_bounds__(256) void k_scanA(const int* __restrict__ cnt,
                                               int* __restrict__ part,
                                               int* __restrict__ bsum, int N) {
  __shared__ int tmp[256];
  int t = threadIdx.x;
  int idx = blockIdx.x * 1024 + t * 4;
  int4 v;
  if (idx + 3 < N) {
    v = *(const int4*)(cnt + idx);
  } else {
    v.x = idx + 0 < N ? cnt[idx + 0] : 0;
    v.y = idx + 1 < N ? cnt[idx + 1] : 0;
    v.z = idx + 2 < N ? cnt[idx + 2] : 0;
    v.w = idx + 3 < N ? cnt[idx + 3] : 0;
  }
  int s = v.x + v.y + v.z + v.w;
  tmp[t] = s;
  __syncthreads();
#pragma unroll
  for (int d = 1; d < 256; d <<= 1) {
    int u = (t >= d) ? tmp[t - d] : 0;
    __syncthreads();
    tmp[t] += u;
    __syncthreads();
  }
  int excl = tmp[t] - s;  // exclusive base for this thread's 4 elems
  int4 o;
  o.x = excl;
  o.y = excl + v.x;
  o.z = excl + v.x + v.y;
  o.w = excl + v.x + v.y + v.z;
  if (idx + 3 < N) {
    *(int4*)(part + idx) = o;
  } else {
    if (idx + 0 < N) part[idx + 0] = o.x;
    if (idx + 1 < N) part[idx + 1] = o.y;
    if (idx + 2 < N) part[idx + 2] = o.z;
    if (idx + 3 < N) part[idx + 3] = o.w;
  }
  if (t == 255) bsum[blockIdx.x] = tmp[255];
}

// B: exclusive scan of bsum[nb] (nb <= 256) in one block
__global__ __launch_bounds__(256) void k_scanB(int* __restrict__ bsum, int nb) {
  __shared__ int tmp[256];
  int t = threadIdx.x;
  int s = (t < nb) ? bsum[t] : 0;
  tmp[t] = s;
  __syncthreads();
#pragma unroll
  for (int d = 1; d < 256; d <<= 1) {
    int u = (t >= d) ? tmp[t - d] : 0;
    __syncthreads();
    tmp[t] += u;
    __syncthreads();
  }
  bsum[t] = tmp[t] - s;
}

// C: rowptr[i] = part[i] + bsum[i>>10]; offs copy; rowptr[N] = E
__global__ void k_scanC(const int* __restrict__ part, const int* __restrict__ bsum,
                        int* __restrict__ rowptr, int* __restrict__ offs, int N, int E) {
  int i = blockIdx.x * blockDim.x + threadIdx.x;
  if (i < N) {
    int v = part[i] + bsum[i >> 10];
    rowptr[i] = v;
    offs[i] = v;
  }
  if (i == 0) rowptr[N] = E;
}

// scatter edges into CSR-by-destination; bake symmetric norm into weight
__global__ void k_fill(const unsigned* __restrict__ ei, const int* __restrict__ flag,
                       const float* __restrict__ ew, const float* __restrict__ dinv,
                       int* __restrict__ offs, int* __restrict__ csrc,
                       float* __restrict__ cw, int E) {
  int f = *flag;
  for (int e = blockIdx.x * blockDim.x + threadIdx.x; e < E; e += gridDim.x * blockDim.x) {
    int r = edge_at(ei, f, e);
    int c = edge_at(ei, f, E + e);
    int p = atomicAdd(&offs[c], 1);
    csrc[p] = r;
    cw[p] = dinv[r] * ew[e] * dinv[c];
  }
}

// ---------------- GEMM1: h = x[M,512] @ W1[128,512]^T ----------------
__global__ __launch_bounds__(256) void k_gemm1(const float* __restrict__ x,
                                               const float* __restrict__ W,
                                               float* __restrict__ h, int M) {
  __shared__ float xs[32][68];
  __shared__ float ws[32][132];
  const int t = threadIdx.x, tx = t & 15, ty = t >> 4;
  const int m0 = blockIdx.x * 64;
  float acc[4][8];
#pragma unroll
  for (int r = 0; r < 4; r++)
#pragma unroll
    for (int c = 0; c < 8; c++) acc[r][c] = 0.f;

  for (int k0 = 0; k0 < IN_C; k0 += 32) {
#pragma unroll
    for (int p = 0; p < 2; p++) {
      int i = t + p * 256, row = i >> 3, kc = i & 7;
      int gr = m0 + row;
      if (gr >= M) gr = M - 1;
      float4 v = *(const float4*)(x + (size_t)gr * IN_C + k0 + kc * 4);
      xs[kc * 4 + 0][row] = v.x;
      xs[kc * 4 + 1][row] = v.y;
      xs[kc * 4 + 2][row] = v.z;
      xs[kc * 4 + 3][row] = v.w;
    }
#pragma unroll
    for (int p = 0; p < 4; p++) {
      int i = t + p * 256, n = i >> 3, kc = i & 7;
      float4 v = *(const float4*)(W + (size_t)n * IN_C + k0 + kc * 4);
      ws[kc * 4 + 0][n] = v.x;
      ws[kc * 4 + 1][n] = v.y;
      ws[kc * 4 + 2][n] = v.z;
      ws[kc * 4 + 3][n] = v.w;
    }
    __syncthreads();
#pragma unroll
    for (int kk = 0; kk < 32; kk++) {
      float4 a = *(const float4*)&xs[kk][ty * 4];
      float4 b0 = *(const float4*)&ws[kk][tx * 4];
      float4 b1 = *(const float4*)&ws[kk][tx * 4 + 64];
      float ar[4] = {a.x, a.y, a.z, a.w};
      float br[8] = {b0.x, b0.y, b0.z, b0.w, b1.x, b1.y, b1.z, b1.w};
#pragma unroll
      for (int r = 0; r < 4; r++)
#pragma unroll
        for (int c = 0; c < 8; c++) acc[r][c] += ar[r] * br[c];
    }
    __syncthreads();
  }
#pragma unroll
  for (int r = 0; r < 4; r++) {
    int gr = m0 + ty * 4 + r;
    if (gr < M) {
      float4 o0 = {acc[r][0], acc[r][1], acc[r][2], acc[r][3]};
      float4 o1 = {acc[r][4], acc[r][5], acc[r][6], acc[r][7]};
      *(float4*)(h + (size_t)gr * HID + tx * 4) = o0;
      *(float4*)(h + (size_t)gr * HID + tx * 4 + 64) = o1;
    }
  }
}

// ---------------- GEMM2: h2 = z[M,128] @ W2[64,128]^T ----------------
__global__ __launch_bounds__(256) void k_gemm2(const float* __restrict__ z,
                                               const float* __restrict__ W,
                                               float* __restrict__ h, int M) {
  __shared__ float zs[32][68];
  __shared__ float ws2[32][68];
  const int t = threadIdx.x, tx = t & 15, ty = t >> 4;
  const int m0 = blockIdx.x * 64;
  float acc[4][4];
#pragma unroll
  for (int r = 0; r < 4; r++)
#pragma unroll
    for (int c = 0; c < 4; c++) acc[r][c] = 0.f;

  for (int k0 = 0; k0 < HID; k0 += 32) {
#pragma unroll
    for (int p = 0; p < 2; p++) {
      int i = t + p * 256, row = i >> 3, kc = i & 7;
      int gr = m0 + row;
      if (gr >= M) gr = M - 1;
      float4 v = *(const float4*)(z + (size_t)gr * HID + k0 + kc * 4);
      zs[kc * 4 + 0][row] = v.x;
      zs[kc * 4 + 1][row] = v.y;
      zs[kc * 4 + 2][row] = v.z;
      zs[kc * 4 + 3][row] = v.w;
    }
#pragma unroll
    for (int p = 0; p < 2; p++) {
      int i = t + p * 256, n = i >> 3, kc = i & 7;
      float4 v = *(const float4*)(W + (size_t)n * HID + k0 + kc * 4);
      ws2[kc * 4 + 0][n] = v.x;
      ws2[kc * 4 + 1][n] = v.y;
      ws2[kc * 4 + 2][n] = v.z;
      ws2[kc * 4 + 3][n] = v.w;
    }
    __syncthreads();
#pragma unroll
    for (int kk = 0; kk < 32; kk++) {
      float4 a = *(const float4*)&zs[kk][ty * 4];
      float4 b = *(const float4*)&ws2[kk][tx * 4];
      float ar[4] = {a.x, a.y, a.z, a.w};
      float br[4] = {b.x, b.y, b.z, b.w};
#pragma unroll
      for (int r = 0; r < 4; r++)
#pragma unroll
        for (int c = 0; c < 4; c++) acc[r][c] += ar[r] * br[c];
    }
    __syncthreads();
  }
#pragma unroll
  for (int r = 0; r < 4; r++) {
    int gr = m0 + ty * 4 + r;
    if (gr < M) {
      float4 o = {acc[r][0], acc[r][1], acc[r][2], acc[r][3]};
      *(float4*)(h + (size_t)gr * HID2 + tx * 4) = o;
    }
  }
}

// ---------------- aggregation (pull over CSR) + bias + PReLU ----------------
__global__ void k_agg1(const float* __restrict__ h, const int* __restrict__ rowptr,
                       const int* __restrict__ csrc, const float* __restrict__ cw,
                       const float* __restrict__ dinv, const float* __restrict__ bias,
                       const float* __restrict__ alpha, float* __restrict__ z, int N) {
  int node = blockIdx.x * 4 + (threadIdx.x >> 6);
  int lane = threadIdx.x & 63;
  if (node >= N) return;
  const float2* hp = (const float2*)h;
  float2 acc = make_float2(0.f, 0.f);
  int s = rowptr[node], epd = rowptr[node + 1];
  for (int e = s; e < epd; e++) {
    int src = csrc[e];
    float wv = cw[e];
    float2 v = hp[(size_t)src * 64 + lane];
    acc.x += wv * v.x;
    acc.y += wv * v.y;
  }
  float di = dinv[node];
  float sw = di * di;
  float2 v = hp[(size_t)node * 64 + lane];
  acc.x += sw * v.x;
  acc.y += sw * v.y;
  acc.x += bias[lane * 2];
  acc.y += bias[lane * 2 + 1];
  float a0 = alpha[lane * 2], a1 = alpha[lane * 2 + 1];
  acc.x = acc.x >= 0.f ? acc.x : a0 * acc.x;
  acc.y = acc.y >= 0.f ? acc.y : a1 * acc.y;
  ((float2*)z)[(size_t)node * 64 + lane] = acc;
}

__global__ void k_agg2(const float* __restrict__ h, const int* __restrict__ rowptr,
                       const int* __restrict__ csrc, const float* __restrict__ cw,
                       const float* __restrict__ dinv, const float* __restrict__ bias,
                       const float* __restrict__ alpha, float* __restrict__ out, int N) {
  int node = blockIdx.x * 4 + (threadIdx.x >> 6);
  int lane = threadIdx.x & 63;
  if (node >= N) return;
  float acc = 0.f;
  int s = rowptr[node], epd = rowptr[node + 1];
  for (int e = s; e < epd; e++) {
    acc += cw[e] * h[(size_t)csrc[e] * HID2 + lane];
  }
  float di = dinv[node];
  acc += di * di * h[(size_t)node * HID2 + lane];
  acc += bias[lane];
  float a = alpha[lane];
  acc = acc >= 0.f ? acc : a * acc;
  out[(size_t)node * HID2 + lane] = acc;
}

extern "C" void kernel_launch(void* const* d_in, const int* in_sizes, int n_in,
                              void* d_out, int out_size, void* d_ws, size_t ws_size,
                              hipStream_t stream) {
  const float* x = (const float*)d_in[0];
  const unsigned* ei = (const unsigned*)d_in[1];
  const float* ew = (const float*)d_in[2];
  const float* W1 = (const float*)d_in[3];
  const float* b1 = (const float*)d_in[4];
  const float* a1 = (const float*)d_in[5];
  const float* W2 = (const float*)d_in[6];
  const float* b2 = (const float*)d_in[7];
  const float* a2 = (const float*)d_in[8];
  float* out = (float*)d_out;

  const int N = in_sizes[0] / IN_C;
  const int E = in_sizes[2];
  const int NB = (N + 1023) / 1024;  // scan blocks (<=256 for N<=262144)

  char* w = (char*)d_ws;
  auto alloc = [&](size_t bytes) -> void* {
    void* p = (void*)w;
    w += (bytes + 255) / 256 * 256;
    return p;
  };
  int* flag = (int*)alloc(4);
  float* deg = (float*)alloc((size_t)N * 4);
  float* dinv = (float*)alloc((size_t)N * 4);
  int* cnt = (int*)alloc((size_t)N * 4);
  int* rowptr = (int*)alloc((size_t)(N + 1) * 4);
  int* offs = (int*)alloc((size_t)N * 4);
  int* part = (int*)alloc((size_t)N * 4);
  int* bsum = (int*)alloc(256 * 4);
  int* csrc = (int*)alloc((size_t)E * 4);
  float* cw = (float*)alloc((size_t)E * 4);
  float* h1 = (float*)alloc((size_t)N * HID * 4);
  float* z1 = (float*)alloc((size_t)N * HID * 4);
  float* h2 = (float*)alloc((size_t)N * HID2 * 4);

  hipMemsetAsync(deg, 0, (size_t)N * 4, stream);
  hipMemsetAsync(cnt, 0, (size_t)N * 4, stream);

  k_detect<<<1, 256, 0, stream>>>(ei, flag);
  k_deg<<<2048, 256, 0, stream>>>(ei, flag, ew, deg, cnt, E);
  k_dinv<<<(N + 255) / 256, 256, 0, stream>>>(deg, dinv, N);
  k_scanA<<<NB, 256, 0, stream>>>(cnt, part, bsum, N);
  k_scanB<<<1, 256, 0, stream>>>(bsum, NB);
  k_scanC<<<(N + 255) / 256, 256, 0, stream>>>(part, bsum, rowptr, offs, N, E);
  k_fill<<<2048, 256, 0, stream>>>(ei, flag, ew, dinv, offs, csrc, cw, E);

  k_gemm1<<<(N + 63) / 64, 256, 0, stream>>>(x, W1, h1, N);
  k_agg1<<<(N + 3) / 4, 256, 0, stream>>>(h1, rowptr, csrc, cw, dinv, b1, a1, z1, N);
  k_gemm2<<<(N + 63) / 64, 256, 0, stream>>>(z1, W2, h2, N);
  k_agg2<<<(N + 3) / 4, 256, 0, stream>>>(h2, rowptr, csrc, cw, dinv, b2, a2, out, N);
}

// Round 4
// 491.007 us; speedup vs baseline: 1.3713x; 1.1453x over previous
//
#include <hip/hip_runtime.h>

#define IN_C 512
#define HID  128
#define HID2 64

typedef __attribute__((ext_vector_type(8))) short short8v;
typedef __attribute__((ext_vector_type(4))) float float4v;

__device__ __forceinline__ unsigned short f2bf(float f) {
  unsigned u = __float_as_uint(f);
  unsigned r = u + 0x7FFF + ((u >> 16) & 1);  // RNE
  return (unsigned short)(r >> 16);
}
__device__ __forceinline__ float bf2f(unsigned short h) {
  return __uint_as_float((unsigned)h << 16);
}
__device__ __forceinline__ uint2 pack4(unsigned short a, unsigned short b,
                                       unsigned short c, unsigned short d) {
  uint2 p;
  p.x = (unsigned)a | ((unsigned)b << 16);
  p.y = (unsigned)c | ((unsigned)d << 16);
  return p;
}

// ---------------- edge_index dtype detection ----------------
__global__ void k_detect(const unsigned* __restrict__ ei, int* __restrict__ flag) {
  __shared__ int nz;
  if (threadIdx.x == 0) nz = 0;
  __syncthreads();
  if (ei[2 * threadIdx.x + 1] != 0u) atomicOr(&nz, 1);
  __syncthreads();
  if (threadIdx.x == 0) *flag = (nz == 0) ? 1 : 0;  // 1 => int64
}

__device__ __forceinline__ int edge_at(const unsigned* __restrict__ ei, int f, int i) {
  return (int)(f ? ei[2 * (size_t)i] : ei[i]);
}

// ---------------- degree + in-degree counts ----------------
__global__ void k_deg(const unsigned* __restrict__ ei, const int* __restrict__ flag,
                      const float* __restrict__ ew, float* __restrict__ deg,
                      int* __restrict__ cnt, int E) {
  int f = *flag;
  for (int e = blockIdx.x * blockDim.x + threadIdx.x; e < E; e += gridDim.x * blockDim.x) {
    int c = edge_at(ei, f, E + e);
    atomicAdd(&deg[c], ew[e]);
    atomicAdd(&cnt[c], 1);
  }
}

__global__ void k_dinv(const float* __restrict__ deg, float* __restrict__ dinv, int N) {
  int i = blockIdx.x * blockDim.x + threadIdx.x;
  if (i < N) {
    float d = deg[i] + 1.0f;  // self loop; always > 0
    float y = rsqrtf(d);
    y = y * (1.5f - 0.5f * d * y * y);  // Newton: ~1 ulp f32
    dinv[i] = y;
  }
}

// ---------------- hierarchical exclusive scan of cnt[N] ----------------
__global__ __launch_bounds__(256) void k_scanA(const int* __restrict__ cnt,
                                               int* __restrict__ part,
                                               int* __restrict__ bsum, int N) {
  __shared__ int tmp[256];
  int t = threadIdx.x;
  int idx = blockIdx.x * 1024 + t * 4;
  int4 v;
  if (idx + 3 < N) {
    v = *(const int4*)(cnt + idx);
  } else {
    v.x = idx + 0 < N ? cnt[idx + 0] : 0;
    v.y = idx + 1 < N ? cnt[idx + 1] : 0;
    v.z = idx + 2 < N ? cnt[idx + 2] : 0;
    v.w = idx + 3 < N ? cnt[idx + 3] : 0;
  }
  int s = v.x + v.y + v.z + v.w;
  tmp[t] = s;
  __syncthreads();
#pragma unroll
  for (int d = 1; d < 256; d <<= 1) {
    int u = (t >= d) ? tmp[t - d] : 0;
    __syncthreads();
    tmp[t] += u;
    __syncthreads();
  }
  int excl = tmp[t] - s;
  int4 o;
  o.x = excl;
  o.y = excl + v.x;
  o.z = excl + v.x + v.y;
  o.w = excl + v.x + v.y + v.z;
  if (idx + 3 < N) {
    *(int4*)(part + idx) = o;
  } else {
    if (idx + 0 < N) part[idx + 0] = o.x;
    if (idx + 1 < N) part[idx + 1] = o.y;
    if (idx + 2 < N) part[idx + 2] = o.z;
    if (idx + 3 < N) part[idx + 3] = o.w;
  }
  if (t == 255) bsum[blockIdx.x] = tmp[255];
}

__global__ __launch_bounds__(256) void k_scanB(int* __restrict__ bsum, int nb) {
  __shared__ int tmp[256];
  int t = threadIdx.x;
  int s = (t < nb) ? bsum[t] : 0;
  tmp[t] = s;
  __syncthreads();
#pragma unroll
  for (int d = 1; d < 256; d <<= 1) {
    int u = (t >= d) ? tmp[t - d] : 0;
    __syncthreads();
    tmp[t] += u;
    __syncthreads();
  }
  bsum[t] = tmp[t] - s;
}

__global__ void k_scanC(const int* __restrict__ part, const int* __restrict__ bsum,
                        int* __restrict__ rowptr, int* __restrict__ offs, int N, int E) {
  int i = blockIdx.x * blockDim.x + threadIdx.x;
  if (i < N) {
    int v = part[i] + bsum[i >> 10];
    rowptr[i] = v;
    offs[i] = v;
  }
  if (i == 0) rowptr[N] = E;
}

// scatter edges into CSR-by-destination; bake symmetric norm into weight
__global__ void k_fill(const unsigned* __restrict__ ei, const int* __restrict__ flag,
                       const float* __restrict__ ew, const float* __restrict__ dinv,
                       int* __restrict__ offs, int* __restrict__ csrc,
                       float* __restrict__ cw, int E) {
  int f = *flag;
  for (int e = blockIdx.x * blockDim.x + threadIdx.x; e < E; e += gridDim.x * blockDim.x) {
    int r = edge_at(ei, f, e);
    int c = edge_at(ei, f, E + e);
    int p = atomicAdd(&offs[c], 1);
    csrc[p] = r;
    cw[p] = dinv[r] * ew[e] * dinv[c];
  }
}

// ---------------- GEMM1 (split-bf16 MFMA): h = x[M,512] @ W1[128,512]^T --------
// Block tile 128x128, 4 waves each 64x64, BK=32.
// LDS layout [kb][row][8] bf16: fragment read = one aligned ds_read_b128,
// 16 consecutive rows x 16B sweep all 32 banks -> conflict-free.
__global__ __launch_bounds__(256) void k_gemm1m(const float* __restrict__ x,
                                                const float* __restrict__ W,
                                                float* __restrict__ h, int M) {
  __shared__ short xh[4][128][8], xl[4][128][8];
  __shared__ short wh[4][128][8], wl[4][128][8];
  const int t = threadIdx.x;
  const int lane = t & 63, w = t >> 6;
  const int wm = (w >> 1) * 64, wn = (w & 1) * 64;
  const int kb = lane >> 4, r16 = lane & 15;
  const int m0 = blockIdx.x * 128;

  float4v acc[4][4];
#pragma unroll
  for (int mi = 0; mi < 4; mi++)
#pragma unroll
    for (int nj = 0; nj < 4; nj++) acc[mi][nj] = (float4v)0.f;

  for (int k0 = 0; k0 < IN_C; k0 += 32) {
    // stage x tile: 128 rows x 32 k = 1024 float4
#pragma unroll
    for (int i = 0; i < 4; i++) {
      int idx = t + i * 256;
      int row = idx >> 3, kc = idx & 7;
      int gr = m0 + row;
      if (gr >= M) gr = M - 1;
      float4 v = *(const float4*)(x + (size_t)gr * IN_C + k0 + kc * 4);
      unsigned short h0 = f2bf(v.x), h1 = f2bf(v.y), h2 = f2bf(v.z), h3 = f2bf(v.w);
      unsigned short l0 = f2bf(v.x - bf2f(h0)), l1 = f2bf(v.y - bf2f(h1));
      unsigned short l2 = f2bf(v.z - bf2f(h2)), l3 = f2bf(v.w - bf2f(h3));
      int kbw = kc >> 1, s = kc & 1;
      *(uint2*)&xh[kbw][row][s * 4] = pack4(h0, h1, h2, h3);
      *(uint2*)&xl[kbw][row][s * 4] = pack4(l0, l1, l2, l3);
    }
    // stage W tile: 128 n x 32 k = 1024 float4
#pragma unroll
    for (int i = 0; i < 4; i++) {
      int idx = t + i * 256;
      int n = idx >> 3, kc = idx & 7;
      float4 v = *(const float4*)(W + (size_t)n * IN_C + k0 + kc * 4);
      unsigned short h0 = f2bf(v.x), h1 = f2bf(v.y), h2 = f2bf(v.z), h3 = f2bf(v.w);
      unsigned short l0 = f2bf(v.x - bf2f(h0)), l1 = f2bf(v.y - bf2f(h1));
      unsigned short l2 = f2bf(v.z - bf2f(h2)), l3 = f2bf(v.w - bf2f(h3));
      int kbw = kc >> 1, s = kc & 1;
      *(uint2*)&wh[kbw][n][s * 4] = pack4(h0, h1, h2, h3);
      *(uint2*)&wl[kbw][n][s * 4] = pack4(l0, l1, l2, l3);
    }
    __syncthreads();

    short8v ah[4], al[4], bh[4], bl[4];
#pragma unroll
    for (int mi = 0; mi < 4; mi++) {
      ah[mi] = *(short8v*)&xh[kb][wm + mi * 16 + r16][0];
      al[mi] = *(short8v*)&xl[kb][wm + mi * 16 + r16][0];
    }
#pragma unroll
    for (int nj = 0; nj < 4; nj++) {
      bh[nj] = *(short8v*)&wh[kb][wn + nj * 16 + r16][0];
      bl[nj] = *(short8v*)&wl[kb][wn + nj * 16 + r16][0];
    }
#pragma unroll
    for (int mi = 0; mi < 4; mi++)
#pragma unroll
      for (int nj = 0; nj < 4; nj++) {
        acc[mi][nj] = __builtin_amdgcn_mfma_f32_16x16x32_bf16(ah[mi], bh[nj], acc[mi][nj], 0, 0, 0);
        acc[mi][nj] = __builtin_amdgcn_mfma_f32_16x16x32_bf16(ah[mi], bl[nj], acc[mi][nj], 0, 0, 0);
        acc[mi][nj] = __builtin_amdgcn_mfma_f32_16x16x32_bf16(al[mi], bh[nj], acc[mi][nj], 0, 0, 0);
      }
    __syncthreads();
  }

  // epilogue: D col = lane&15, row = (lane>>4)*4 + b
#pragma unroll
  for (int mi = 0; mi < 4; mi++)
#pragma unroll
    for (int nj = 0; nj < 4; nj++) {
#pragma unroll
      for (int b = 0; b < 4; b++) {
        int grow = m0 + wm + mi * 16 + (lane >> 4) * 4 + b;
        int gcol = wn + nj * 16 + r16;
        if (grow < M) h[(size_t)grow * HID + gcol] = acc[mi][nj][b];
      }
    }
}

// ---------------- GEMM2 (split-bf16 MFMA): h2 = z[M,128] @ W2[64,128]^T --------
// Block tile 128x64, 4 waves: 2(M) x 2(N), wave tile 64x32. BK=32, 4 K-steps.
__global__ __launch_bounds__(256) void k_gemm2m(const float* __restrict__ z,
                                                const float* __restrict__ W,
                                                float* __restrict__ h, int M) {
  __shared__ short zh[4][128][8], zl[4][128][8];
  __shared__ short wh[4][64][8], wl[4][64][8];
  const int t = threadIdx.x;
  const int lane = t & 63, w = t >> 6;
  const int wm = (w >> 1) * 64, wn = (w & 1) * 32;
  const int kb = lane >> 4, r16 = lane & 15;
  const int m0 = blockIdx.x * 128;

  float4v acc[4][2];
#pragma unroll
  for (int mi = 0; mi < 4; mi++)
#pragma unroll
    for (int nj = 0; nj < 2; nj++) acc[mi][nj] = (float4v)0.f;

  for (int k0 = 0; k0 < HID; k0 += 32) {
#pragma unroll
    for (int i = 0; i < 4; i++) {  // z tile: 128 rows x 32 k
      int idx = t + i * 256;
      int row = idx >> 3, kc = idx & 7;
      int gr = m0 + row;
      if (gr >= M) gr = M - 1;
      float4 v = *(const float4*)(z + (size_t)gr * HID + k0 + kc * 4);
      unsigned short h0 = f2bf(v.x), h1 = f2bf(v.y), h2 = f2bf(v.z), h3 = f2bf(v.w);
      unsigned short l0 = f2bf(v.x - bf2f(h0)), l1 = f2bf(v.y - bf2f(h1));
      unsigned short l2 = f2bf(v.z - bf2f(h2)), l3 = f2bf(v.w - bf2f(h3));
      int kbw = kc >> 1, s = kc & 1;
      *(uint2*)&zh[kbw][row][s * 4] = pack4(h0, h1, h2, h3);
      *(uint2*)&zl[kbw][row][s * 4] = pack4(l0, l1, l2, l3);
    }
#pragma unroll
    for (int i = 0; i < 2; i++) {  // W2 tile: 64 n x 32 k = 512 float4
      int idx = t + i * 256;
      int n = idx >> 3, kc = idx & 7;
      float4 v = *(const float4*)(W + (size_t)n * HID + k0 + kc * 4);
      unsigned short h0 = f2bf(v.x), h1 = f2bf(v.y), h2 = f2bf(v.z), h3 = f2bf(v.w);
      unsigned short l0 = f2bf(v.x - bf2f(h0)), l1 = f2bf(v.y - bf2f(h1));
      unsigned short l2 = f2bf(v.z - bf2f(h2)), l3 = f2bf(v.w - bf2f(h3));
      int kbw = kc >> 1, s = kc & 1;
      *(uint2*)&wh[kbw][n][s * 4] = pack4(h0, h1, h2, h3);
      *(uint2*)&wl[kbw][n][s * 4] = pack4(l0, l1, l2, l3);
    }
    __syncthreads();

    short8v ah[4], al[4], bh[2], bl[2];
#pragma unroll
    for (int mi = 0; mi < 4; mi++) {
      ah[mi] = *(short8v*)&zh[kb][wm + mi * 16 + r16][0];
      al[mi] = *(short8v*)&zl[kb][wm + mi * 16 + r16][0];
    }
#pragma unroll
    for (int nj = 0; nj < 2; nj++) {
      bh[nj] = *(short8v*)&wh[kb][wn + nj * 16 + r16][0];
      bl[nj] = *(short8v*)&wl[kb][wn + nj * 16 + r16][0];
    }
#pragma unroll
    for (int mi = 0; mi < 4; mi++)
#pragma unroll
      for (int nj = 0; nj < 2; nj++) {
        acc[mi][nj] = __builtin_amdgcn_mfma_f32_16x16x32_bf16(ah[mi], bh[nj], acc[mi][nj], 0, 0, 0);
        acc[mi][nj] = __builtin_amdgcn_mfma_f32_16x16x32_bf16(ah[mi], bl[nj], acc[mi][nj], 0, 0, 0);
        acc[mi][nj] = __builtin_amdgcn_mfma_f32_16x16x32_bf16(al[mi], bh[nj], acc[mi][nj], 0, 0, 0);
      }
    __syncthreads();
  }

#pragma unroll
  for (int mi = 0; mi < 4; mi++)
#pragma unroll
    for (int nj = 0; nj < 2; nj++) {
#pragma unroll
      for (int b = 0; b < 4; b++) {
        int grow = m0 + wm + mi * 16 + (lane >> 4) * 4 + b;
        int gcol = wn + nj * 16 + r16;
        if (grow < M) h[(size_t)grow * HID2 + gcol] = acc[mi][nj][b];
      }
    }
}

// ---------------- aggregation (pull over CSR) + bias + PReLU ----------------
__global__ void k_agg1(const float* __restrict__ h, const int* __restrict__ rowptr,
                       const int* __restrict__ csrc, const float* __restrict__ cw,
                       const float* __restrict__ dinv, const float* __restrict__ bias,
                       const float* __restrict__ alpha, float* __restrict__ z, int N) {
  int node = blockIdx.x * 4 + (threadIdx.x >> 6);
  int lane = threadIdx.x & 63;
  if (node >= N) return;
  const float2* hp = (const float2*)h;
  float2 acc = make_float2(0.f, 0.f);
  int s = rowptr[node], epd = rowptr[node + 1];
  for (int e = s; e < epd; e++) {
    int src = csrc[e];
    float wv = cw[e];
    float2 v = hp[(size_t)src * 64 + lane];
    acc.x += wv * v.x;
    acc.y += wv * v.y;
  }
  float di = dinv[node];
  float sw = di * di;
  float2 v = hp[(size_t)node * 64 + lane];
  acc.x += sw * v.x;
  acc.y += sw * v.y;
  acc.x += bias[lane * 2];
  acc.y += bias[lane * 2 + 1];
  float a0 = alpha[lane * 2], a1 = alpha[lane * 2 + 1];
  acc.x = acc.x >= 0.f ? acc.x : a0 * acc.x;
  acc.y = acc.y >= 0.f ? acc.y : a1 * acc.y;
  ((float2*)z)[(size_t)node * 64 + lane] = acc;
}

__global__ void k_agg2(const float* __restrict__ h, const int* __restrict__ rowptr,
                       const int* __restrict__ csrc, const float* __restrict__ cw,
                       const float* __restrict__ dinv, const float* __restrict__ bias,
                       const float* __restrict__ alpha, float* __restrict__ out, int N) {
  int node = blockIdx.x * 4 + (threadIdx.x >> 6);
  int lane = threadIdx.x & 63;
  if (node >= N) return;
  float acc = 0.f;
  int s = rowptr[node], epd = rowptr[node + 1];
  for (int e = s; e < epd; e++) {
    acc += cw[e] * h[(size_t)csrc[e] * HID2 + lane];
  }
  float di = dinv[node];
  acc += di * di * h[(size_t)node * HID2 + lane];
  acc += bias[lane];
  float a = alpha[lane];
  acc = acc >= 0.f ? acc : a * acc;
  out[(size_t)node * HID2 + lane] = acc;
}

extern "C" void kernel_launch(void* const* d_in, const int* in_sizes, int n_in,
                              void* d_out, int out_size, void* d_ws, size_t ws_size,
                              hipStream_t stream) {
  const float* x = (const float*)d_in[0];
  const unsigned* ei = (const unsigned*)d_in[1];
  const float* ew = (const float*)d_in[2];
  const float* W1 = (const float*)d_in[3];
  const float* b1 = (const float*)d_in[4];
  const float* a1 = (const float*)d_in[5];
  const float* W2 = (const float*)d_in[6];
  const float* b2 = (const float*)d_in[7];
  const float* a2 = (const float*)d_in[8];
  float* out = (float*)d_out;

  const int N = in_sizes[0] / IN_C;
  const int E = in_sizes[2];
  const int NB = (N + 1023) / 1024;

  char* w = (char*)d_ws;
  auto alloc = [&](size_t bytes) -> void* {
    void* p = (void*)w;
    w += (bytes + 255) / 256 * 256;
    return p;
  };
  int* flag = (int*)alloc(4);
  float* deg = (float*)alloc((size_t)N * 4);
  float* dinv = (float*)alloc((size_t)N * 4);
  int* cnt = (int*)alloc((size_t)N * 4);
  int* rowptr = (int*)alloc((size_t)(N + 1) * 4);
  int* offs = (int*)alloc((size_t)N * 4);
  int* part = (int*)alloc((size_t)N * 4);
  int* bsum = (int*)alloc(256 * 4);
  int* csrc = (int*)alloc((size_t)E * 4);
  float* cw = (float*)alloc((size_t)E * 4);
  float* h1 = (float*)alloc((size_t)N * HID * 4);
  float* z1 = (float*)alloc((size_t)N * HID * 4);
  float* h2 = (float*)alloc((size_t)N * HID2 * 4);

  hipMemsetAsync(deg, 0, (size_t)N * 4, stream);
  hipMemsetAsync(cnt, 0, (size_t)N * 4, stream);

  k_detect<<<1, 256, 0, stream>>>(ei, flag);
  k_deg<<<2048, 256, 0, stream>>>(ei, flag, ew, deg, cnt, E);
  k_dinv<<<(N + 255) / 256, 256, 0, stream>>>(deg, dinv, N);
  k_scanA<<<NB, 256, 0, stream>>>(cnt, part, bsum, N);
  k_scanB<<<1, 256, 0, stream>>>(bsum, NB);
  k_scanC<<<(N + 255) / 256, 256, 0, stream>>>(part, bsum, rowptr, offs, N, E);
  k_fill<<<2048, 256, 0, stream>>>(ei, flag, ew, dinv, offs, csrc, cw, E);

  k_gemm1m<<<(N + 127) / 128, 256, 0, stream>>>(x, W1, h1, N);
  k_agg1<<<(N + 3) / 4, 256, 0, stream>>>(h1, rowptr, csrc, cw, dinv, b1, a1, z1, N);
  k_gemm2m<<<(N + 127) / 128, 256, 0, stream>>>(z1, W2, h2, N);
  k_agg2<<<(N + 3) / 4, 256, 0, stream>>>(h2, rowptr, csrc, cw, dinv, b2, a2, out, N);
}

// Round 5
// 434.431 us; speedup vs baseline: 1.5499x; 1.1302x over previous
//
#include <hip/hip_runtime.h>
#include <hip/hip_fp16.h>

#define IN_C 512
#define HID  128
#define HID2 64

typedef __attribute__((ext_vector_type(8))) short short8v;
typedef __attribute__((ext_vector_type(4))) float float4v;

__device__ __forceinline__ unsigned short f2bf(float f) {
  unsigned u = __float_as_uint(f);
  unsigned r = u + 0x7FFF + ((u >> 16) & 1);  // RNE
  return (unsigned short)(r >> 16);
}
__device__ __forceinline__ float bf2f(unsigned short h) {
  return __uint_as_float((unsigned)h << 16);
}
__device__ __forceinline__ uint2 pack4(unsigned short a, unsigned short b,
                                       unsigned short c, unsigned short d) {
  uint2 p;
  p.x = (unsigned)a | ((unsigned)b << 16);
  p.y = (unsigned)c | ((unsigned)d << 16);
  return p;
}

// ---------------- edge_index dtype detection ----------------
__global__ void k_detect(const unsigned* __restrict__ ei, int* __restrict__ flag) {
  __shared__ int nz;
  if (threadIdx.x == 0) nz = 0;
  __syncthreads();
  if (ei[2 * threadIdx.x + 1] != 0u) atomicOr(&nz, 1);
  __syncthreads();
  if (threadIdx.x == 0) *flag = (nz == 0) ? 1 : 0;  // 1 => int64
}

__device__ __forceinline__ int edge_at(const unsigned* __restrict__ ei, int f, int i) {
  return (int)(f ? ei[2 * (size_t)i] : ei[i]);
}

// ---------------- degree + in-degree counts (2 edges/thread) ----------------
__global__ void k_deg(const unsigned* __restrict__ ei, const int* __restrict__ flag,
                      const float* __restrict__ ew, float* __restrict__ deg,
                      int* __restrict__ cnt, int E) {
  int f = *flag;
  int stride = gridDim.x * blockDim.x * 2;
  for (int e = (blockIdx.x * blockDim.x + threadIdx.x) * 2; e < E; e += stride) {
    int c0, c1 = -1;
    if (f) {
      if (e + 1 < E) {
        uint4 v = *(const uint4*)(ei + 2 * (size_t)(E + e));
        c0 = (int)v.x;
        c1 = (int)v.z;
      } else {
        c0 = (int)ei[2 * (size_t)(E + e)];
      }
    } else {
      if (e + 1 < E) {
        uint2 v = *(const uint2*)(ei + (size_t)E + e);
        c0 = (int)v.x;
        c1 = (int)v.y;
      } else {
        c0 = (int)ei[(size_t)E + e];
      }
    }
    if (e + 1 < E) {
      float2 w = *(const float2*)(ew + e);
      atomicAdd(&deg[c0], w.x);
      atomicAdd(&cnt[c0], 1);
      atomicAdd(&deg[c1], w.y);
      atomicAdd(&cnt[c1], 1);
    } else {
      atomicAdd(&deg[c0], ew[e]);
      atomicAdd(&cnt[c0], 1);
    }
  }
}

__global__ void k_dinv(const float* __restrict__ deg, float* __restrict__ dinv, int N) {
  int i = blockIdx.x * blockDim.x + threadIdx.x;
  if (i < N) {
    float d = deg[i] + 1.0f;  // self loop; always > 0
    float y = rsqrtf(d);
    y = y * (1.5f - 0.5f * d * y * y);  // Newton: ~1 ulp f32
    dinv[i] = y;
  }
}

// ---------------- hierarchical exclusive scan of cnt[N] ----------------
__global__ __launch_bounds__(256) void k_scanA(const int* __restrict__ cnt,
                                               int* __restrict__ part,
                                               int* __restrict__ bsum, int N) {
  __shared__ int tmp[256];
  int t = threadIdx.x;
  int idx = blockIdx.x * 1024 + t * 4;
  int4 v;
  if (idx + 3 < N) {
    v = *(const int4*)(cnt + idx);
  } else {
    v.x = idx + 0 < N ? cnt[idx + 0] : 0;
    v.y = idx + 1 < N ? cnt[idx + 1] : 0;
    v.z = idx + 2 < N ? cnt[idx + 2] : 0;
    v.w = idx + 3 < N ? cnt[idx + 3] : 0;
  }
  int s = v.x + v.y + v.z + v.w;
  tmp[t] = s;
  __syncthreads();
#pragma unroll
  for (int d = 1; d < 256; d <<= 1) {
    int u = (t >= d) ? tmp[t - d] : 0;
    __syncthreads();
    tmp[t] += u;
    __syncthreads();
  }
  int excl = tmp[t] - s;
  int4 o;
  o.x = excl;
  o.y = excl + v.x;
  o.z = excl + v.x + v.y;
  o.w = excl + v.x + v.y + v.z;
  if (idx + 3 < N) {
    *(int4*)(part + idx) = o;
  } else {
    if (idx + 0 < N) part[idx + 0] = o.x;
    if (idx + 1 < N) part[idx + 1] = o.y;
    if (idx + 2 < N) part[idx + 2] = o.z;
    if (idx + 3 < N) part[idx + 3] = o.w;
  }
  if (t == 255) bsum[blockIdx.x] = tmp[255];
}

__global__ __launch_bounds__(256) void k_scanB(int* __restrict__ bsum, int nb) {
  __shared__ int tmp[256];
  int t = threadIdx.x;
  int s = (t < nb) ? bsum[t] : 0;
  tmp[t] = s;
  __syncthreads();
#pragma unroll
  for (int d = 1; d < 256; d <<= 1) {
    int u = (t >= d) ? tmp[t - d] : 0;
    __syncthreads();
    tmp[t] += u;
    __syncthreads();
  }
  bsum[t] = tmp[t] - s;
}

__global__ void k_scanC(const int* __restrict__ part, const int* __restrict__ bsum,
                        int* __restrict__ rowptr, int* __restrict__ offs, int N, int E) {
  int i = blockIdx.x * blockDim.x + threadIdx.x;
  if (i < N) {
    int v = part[i] + bsum[i >> 10];
    rowptr[i] = v;
    offs[i] = v;
  }
  if (i == 0) rowptr[N] = E;
}

// scatter edges into CSR-by-destination; bake symmetric norm into weight
__global__ void k_fill(const unsigned* __restrict__ ei, const int* __restrict__ flag,
                       const float* __restrict__ ew, const float* __restrict__ dinv,
                       int* __restrict__ offs, int* __restrict__ csrc,
                       float* __restrict__ cw, int E) {
  int f = *flag;
  int stride = gridDim.x * blockDim.x * 2;
  for (int e = (blockIdx.x * blockDim.x + threadIdx.x) * 2; e < E; e += stride) {
    int r0, c0, r1 = -1, c1 = -1;
    if (f) {
      if (e + 1 < E) {
        uint4 vr = *(const uint4*)(ei + 2 * (size_t)e);
        uint4 vc = *(const uint4*)(ei + 2 * (size_t)(E + e));
        r0 = (int)vr.x;
        r1 = (int)vr.z;
        c0 = (int)vc.x;
        c1 = (int)vc.z;
      } else {
        r0 = (int)ei[2 * (size_t)e];
        c0 = (int)ei[2 * (size_t)(E + e)];
      }
    } else {
      if (e + 1 < E) {
        uint2 vr = *(const uint2*)(ei + e);
        uint2 vc = *(const uint2*)(ei + (size_t)E + e);
        r0 = (int)vr.x;
        r1 = (int)vr.y;
        c0 = (int)vc.x;
        c1 = (int)vc.y;
      } else {
        r0 = (int)ei[e];
        c0 = (int)ei[(size_t)E + e];
      }
    }
    if (e + 1 < E) {
      float2 w = *(const float2*)(ew + e);
      int p0 = atomicAdd(&offs[c0], 1);
      csrc[p0] = r0;
      cw[p0] = dinv[r0] * w.x * dinv[c0];
      int p1 = atomicAdd(&offs[c1], 1);
      csrc[p1] = r1;
      cw[p1] = dinv[r1] * w.y * dinv[c1];
    } else {
      int p0 = atomicAdd(&offs[c0], 1);
      csrc[p0] = r0;
      cw[p0] = dinv[r0] * ew[e] * dinv[c0];
    }
  }
}

// ---------------- GEMM1 (split-bf16 MFMA): h = x[M,512] @ W1[128,512]^T --------
// Block tile 128x128, 4 waves each 64x64, BK=32. Output fp16.
__global__ __launch_bounds__(256) void k_gemm1m(const float* __restrict__ x,
                                                const float* __restrict__ W,
                                                __half* __restrict__ h, int M) {
  __shared__ short xh[4][128][8], xl[4][128][8];
  __shared__ short wh[4][128][8], wl[4][128][8];
  const int t = threadIdx.x;
  const int lane = t & 63, w = t >> 6;
  const int wm = (w >> 1) * 64, wn = (w & 1) * 64;
  const int kb = lane >> 4, r16 = lane & 15;
  const int m0 = blockIdx.x * 128;

  float4v acc[4][4];
#pragma unroll
  for (int mi = 0; mi < 4; mi++)
#pragma unroll
    for (int nj = 0; nj < 4; nj++) acc[mi][nj] = (float4v)0.f;

  for (int k0 = 0; k0 < IN_C; k0 += 32) {
#pragma unroll
    for (int i = 0; i < 4; i++) {
      int idx = t + i * 256;
      int row = idx >> 3, kc = idx & 7;
      int gr = m0 + row;
      if (gr >= M) gr = M - 1;
      float4 v = *(const float4*)(x + (size_t)gr * IN_C + k0 + kc * 4);
      unsigned short h0 = f2bf(v.x), h1 = f2bf(v.y), h2 = f2bf(v.z), h3 = f2bf(v.w);
      unsigned short l0 = f2bf(v.x - bf2f(h0)), l1 = f2bf(v.y - bf2f(h1));
      unsigned short l2 = f2bf(v.z - bf2f(h2)), l3 = f2bf(v.w - bf2f(h3));
      int kbw = kc >> 1, s = kc & 1;
      *(uint2*)&xh[kbw][row][s * 4] = pack4(h0, h1, h2, h3);
      *(uint2*)&xl[kbw][row][s * 4] = pack4(l0, l1, l2, l3);
    }
#pragma unroll
    for (int i = 0; i < 4; i++) {
      int idx = t + i * 256;
      int n = idx >> 3, kc = idx & 7;
      float4 v = *(const float4*)(W + (size_t)n * IN_C + k0 + kc * 4);
      unsigned short h0 = f2bf(v.x), h1 = f2bf(v.y), h2 = f2bf(v.z), h3 = f2bf(v.w);
      unsigned short l0 = f2bf(v.x - bf2f(h0)), l1 = f2bf(v.y - bf2f(h1));
      unsigned short l2 = f2bf(v.z - bf2f(h2)), l3 = f2bf(v.w - bf2f(h3));
      int kbw = kc >> 1, s = kc & 1;
      *(uint2*)&wh[kbw][n][s * 4] = pack4(h0, h1, h2, h3);
      *(uint2*)&wl[kbw][n][s * 4] = pack4(l0, l1, l2, l3);
    }
    __syncthreads();

    short8v ah[4], al[4], bh[4], bl[4];
#pragma unroll
    for (int mi = 0; mi < 4; mi++) {
      ah[mi] = *(short8v*)&xh[kb][wm + mi * 16 + r16][0];
      al[mi] = *(short8v*)&xl[kb][wm + mi * 16 + r16][0];
    }
#pragma unroll
    for (int nj = 0; nj < 4; nj++) {
      bh[nj] = *(short8v*)&wh[kb][wn + nj * 16 + r16][0];
      bl[nj] = *(short8v*)&wl[kb][wn + nj * 16 + r16][0];
    }
#pragma unroll
    for (int mi = 0; mi < 4; mi++)
#pragma unroll
      for (int nj = 0; nj < 4; nj++) {
        acc[mi][nj] = __builtin_amdgcn_mfma_f32_16x16x32_bf16(ah[mi], bh[nj], acc[mi][nj], 0, 0, 0);
        acc[mi][nj] = __builtin_amdgcn_mfma_f32_16x16x32_bf16(ah[mi], bl[nj], acc[mi][nj], 0, 0, 0);
        acc[mi][nj] = __builtin_amdgcn_mfma_f32_16x16x32_bf16(al[mi], bh[nj], acc[mi][nj], 0, 0, 0);
      }
    __syncthreads();
  }

  // epilogue: D col = lane&15, row = (lane>>4)*4 + b ; store fp16
#pragma unroll
  for (int mi = 0; mi < 4; mi++)
#pragma unroll
    for (int nj = 0; nj < 4; nj++) {
#pragma unroll
      for (int b = 0; b < 4; b++) {
        int grow = m0 + wm + mi * 16 + (lane >> 4) * 4 + b;
        int gcol = wn + nj * 16 + r16;
        if (grow < M) h[(size_t)grow * HID + gcol] = __float2half(acc[mi][nj][b]);
      }
    }
}

// ---------------- GEMM2 (split-bf16 MFMA): h2 = z[M,128] @ W2[64,128]^T --------
__global__ __launch_bounds__(256) void k_gemm2m(const float* __restrict__ z,
                                                const float* __restrict__ W,
                                                __half* __restrict__ h, int M) {
  __shared__ short zh[4][128][8], zl[4][128][8];
  __shared__ short wh[4][64][8], wl[4][64][8];
  const int t = threadIdx.x;
  const int lane = t & 63, w = t >> 6;
  const int wm = (w >> 1) * 64, wn = (w & 1) * 32;
  const int kb = lane >> 4, r16 = lane & 15;
  const int m0 = blockIdx.x * 128;

  float4v acc[4][2];
#pragma unroll
  for (int mi = 0; mi < 4; mi++)
#pragma unroll
    for (int nj = 0; nj < 2; nj++) acc[mi][nj] = (float4v)0.f;

  for (int k0 = 0; k0 < HID; k0 += 32) {
#pragma unroll
    for (int i = 0; i < 4; i++) {
      int idx = t + i * 256;
      int row = idx >> 3, kc = idx & 7;
      int gr = m0 + row;
      if (gr >= M) gr = M - 1;
      float4 v = *(const float4*)(z + (size_t)gr * HID + k0 + kc * 4);
      unsigned short h0 = f2bf(v.x), h1 = f2bf(v.y), h2 = f2bf(v.z), h3 = f2bf(v.w);
      unsigned short l0 = f2bf(v.x - bf2f(h0)), l1 = f2bf(v.y - bf2f(h1));
      unsigned short l2 = f2bf(v.z - bf2f(h2)), l3 = f2bf(v.w - bf2f(h3));
      int kbw = kc >> 1, s = kc & 1;
      *(uint2*)&zh[kbw][row][s * 4] = pack4(h0, h1, h2, h3);
      *(uint2*)&zl[kbw][row][s * 4] = pack4(l0, l1, l2, l3);
    }
#pragma unroll
    for (int i = 0; i < 2; i++) {
      int idx = t + i * 256;
      int n = idx >> 3, kc = idx & 7;
      float4 v = *(const float4*)(W + (size_t)n * HID + k0 + kc * 4);
      unsigned short h0 = f2bf(v.x), h1 = f2bf(v.y), h2 = f2bf(v.z), h3 = f2bf(v.w);
      unsigned short l0 = f2bf(v.x - bf2f(h0)), l1 = f2bf(v.y - bf2f(h1));
      unsigned short l2 = f2bf(v.z - bf2f(h2)), l3 = f2bf(v.w - bf2f(h3));
      int kbw = kc >> 1, s = kc & 1;
      *(uint2*)&wh[kbw][n][s * 4] = pack4(h0, h1, h2, h3);
      *(uint2*)&wl[kbw][n][s * 4] = pack4(l0, l1, l2, l3);
    }
    __syncthreads();

    short8v ah[4], al[4], bh[2], bl[2];
#pragma unroll
    for (int mi = 0; mi < 4; mi++) {
      ah[mi] = *(short8v*)&zh[kb][wm + mi * 16 + r16][0];
      al[mi] = *(short8v*)&zl[kb][wm + mi * 16 + r16][0];
    }
#pragma unroll
    for (int nj = 0; nj < 2; nj++) {
      bh[nj] = *(short8v*)&wh[kb][wn + nj * 16 + r16][0];
      bl[nj] = *(short8v*)&wl[kb][wn + nj * 16 + r16][0];
    }
#pragma unroll
    for (int mi = 0; mi < 4; mi++)
#pragma unroll
      for (int nj = 0; nj < 2; nj++) {
        acc[mi][nj] = __builtin_amdgcn_mfma_f32_16x16x32_bf16(ah[mi], bh[nj], acc[mi][nj], 0, 0, 0);
        acc[mi][nj] = __builtin_amdgcn_mfma_f32_16x16x32_bf16(ah[mi], bl[nj], acc[mi][nj], 0, 0, 0);
        acc[mi][nj] = __builtin_amdgcn_mfma_f32_16x16x32_bf16(al[mi], bh[nj], acc[mi][nj], 0, 0, 0);
      }
    __syncthreads();
  }

#pragma unroll
  for (int mi = 0; mi < 4; mi++)
#pragma unroll
    for (int nj = 0; nj < 2; nj++) {
#pragma unroll
      for (int b = 0; b < 4; b++) {
        int grow = m0 + wm + mi * 16 + (lane >> 4) * 4 + b;
        int gcol = wn + nj * 16 + r16;
        if (grow < M) h[(size_t)grow * HID2 + gcol] = __float2half(acc[mi][nj][b]);
      }
    }
}

// ---------------- aggregation (pull over CSR, fp16 gather) + bias + PReLU -------
// one wave per node; 64 lanes x half2 = 128 features; edge meta prefetched
// into lane registers and broadcast via shfl (kills dependent-load latency).
__global__ void k_agg1(const __half* __restrict__ h, const int* __restrict__ rowptr,
                       const int* __restrict__ csrc, const float* __restrict__ cw,
                       const float* __restrict__ dinv, const float* __restrict__ bias,
                       const float* __restrict__ alpha, float* __restrict__ z, int N) {
  int node = blockIdx.x * 4 + (threadIdx.x >> 6);
  int lane = threadIdx.x & 63;
  if (node >= N) return;
  const __half2* hp = (const __half2*)h;
  float2 acc = make_float2(0.f, 0.f);
  int s = rowptr[node];
  int dg = rowptr[node + 1] - s;
  for (int base = 0; base < dg; base += 64) {
    int k = base + lane;
    int msrc = 0;
    float mw = 0.f;
    if (k < dg) {
      msrc = csrc[s + k];
      mw = cw[s + k];
    }
    int cnt = min(64, dg - base);
    for (int j = 0; j < cnt; j++) {
      int src = __shfl(msrc, j);
      float wv = __shfl(mw, j);
      float2 v = __half22float2(hp[(size_t)src * 64 + lane]);
      acc.x += wv * v.x;
      acc.y += wv * v.y;
    }
  }
  float di = dinv[node];
  float sw = di * di;
  float2 v = __half22float2(hp[(size_t)node * 64 + lane]);
  acc.x += sw * v.x;
  acc.y += sw * v.y;
  acc.x += bias[lane * 2];
  acc.y += bias[lane * 2 + 1];
  float a0 = alpha[lane * 2], a1 = alpha[lane * 2 + 1];
  acc.x = acc.x >= 0.f ? acc.x : a0 * acc.x;
  acc.y = acc.y >= 0.f ? acc.y : a1 * acc.y;
  ((float2*)z)[(size_t)node * 64 + lane] = acc;
}

// one wave per node; 64 lanes = 64 features (one 128B line per edge)
__global__ void k_agg2(const __half* __restrict__ h, const int* __restrict__ rowptr,
                       const int* __restrict__ csrc, const float* __restrict__ cw,
                       const float* __restrict__ dinv, const float* __restrict__ bias,
                       const float* __restrict__ alpha, float* __restrict__ out, int N) {
  int node = blockIdx.x * 4 + (threadIdx.x >> 6);
  int lane = threadIdx.x & 63;
  if (node >= N) return;
  float acc = 0.f;
  int s = rowptr[node];
  int dg = rowptr[node + 1] - s;
  for (int base = 0; base < dg; base += 64) {
    int k = base + lane;
    int msrc = 0;
    float mw = 0.f;
    if (k < dg) {
      msrc = csrc[s + k];
      mw = cw[s + k];
    }
    int cnt = min(64, dg - base);
    for (int j = 0; j < cnt; j++) {
      int src = __shfl(msrc, j);
      float wv = __shfl(mw, j);
      acc += wv * __half2float(h[(size_t)src * HID2 + lane]);
    }
  }
  float di = dinv[node];
  acc += di * di * __half2float(h[(size_t)node * HID2 + lane]);
  acc += bias[lane];
  float a = alpha[lane];
  acc = acc >= 0.f ? acc : a * acc;
  out[(size_t)node * HID2 + lane] = acc;
}

extern "C" void kernel_launch(void* const* d_in, const int* in_sizes, int n_in,
                              void* d_out, int out_size, void* d_ws, size_t ws_size,
                              hipStream_t stream) {
  const float* x = (const float*)d_in[0];
  const unsigned* ei = (const unsigned*)d_in[1];
  const float* ew = (const float*)d_in[2];
  const float* W1 = (const float*)d_in[3];
  const float* b1 = (const float*)d_in[4];
  const float* a1 = (const float*)d_in[5];
  const float* W2 = (const float*)d_in[6];
  const float* b2 = (const float*)d_in[7];
  const float* a2 = (const float*)d_in[8];
  float* out = (float*)d_out;

  const int N = in_sizes[0] / IN_C;
  const int E = in_sizes[2];
  const int NB = (N + 1023) / 1024;

  char* w = (char*)d_ws;
  auto alloc = [&](size_t bytes) -> void* {
    void* p = (void*)w;
    w += (bytes + 255) / 256 * 256;
    return p;
  };
  int* flag = (int*)alloc(4);
  float* deg = (float*)alloc((size_t)N * 4);
  float* dinv = (float*)alloc((size_t)N * 4);
  int* cnt = (int*)alloc((size_t)N * 4);
  int* rowptr = (int*)alloc((size_t)(N + 1) * 4);
  int* offs = (int*)alloc((size_t)N * 4);
  int* part = (int*)alloc((size_t)N * 4);
  int* bsum = (int*)alloc(256 * 4);
  int* csrc = (int*)alloc((size_t)E * 4);
  float* cw = (float*)alloc((size_t)E * 4);
  __half* h1 = (__half*)alloc((size_t)N * HID * 2);
  float* z1 = (float*)alloc((size_t)N * HID * 4);
  __half* h2 = (__half*)alloc((size_t)N * HID2 * 2);

  hipMemsetAsync(deg, 0, (size_t)N * 4, stream);
  hipMemsetAsync(cnt, 0, (size_t)N * 4, stream);

  k_detect<<<1, 256, 0, stream>>>(ei, flag);
  k_deg<<<1024, 256, 0, stream>>>(ei, flag, ew, deg, cnt, E);
  k_dinv<<<(N + 255) / 256, 256, 0, stream>>>(deg, dinv, N);
  k_scanA<<<NB, 256, 0, stream>>>(cnt, part, bsum, N);
  k_scanB<<<1, 256, 0, stream>>>(bsum, NB);
  k_scanC<<<(N + 255) / 256, 256, 0, stream>>>(part, bsum, rowptr, offs, N, E);
  k_fill<<<1024, 256, 0, stream>>>(ei, flag, ew, dinv, offs, csrc, cw, E);

  k_gemm1m<<<(N + 127) / 128, 256, 0, stream>>>(x, W1, h1, N);
  k_agg1<<<(N + 3) / 4, 256, 0, stream>>>(h1, rowptr, csrc, cw, dinv, b1, a1, z1, N);
  k_gemm2m<<<(N + 127) / 128, 256, 0, stream>>>(z1, W2, h2, N);
  k_agg2<<<(N + 3) / 4, 256, 0, stream>>>(h2, rowptr, csrc, cw, dinv, b2, a2, out, N);
}

// Round 6
// 393.053 us; speedup vs baseline: 1.7131x; 1.1053x over previous
//
#include <hip/hip_runtime.h>
#include <hip/hip_fp16.h>

#define IN_C 512
#define HID  128
#define HID2 64
#define CPAD 32  // counter padding: 32 ints = 128B per node

typedef __attribute__((ext_vector_type(8))) short short8v;
typedef __attribute__((ext_vector_type(4))) float float4v;

__device__ __forceinline__ unsigned short f2bf(float f) {
  unsigned u = __float_as_uint(f);
  unsigned r = u + 0x7FFF + ((u >> 16) & 1);  // RNE
  return (unsigned short)(r >> 16);
}
__device__ __forceinline__ float bf2f(unsigned short h) {
  return __uint_as_float((unsigned)h << 16);
}
__device__ __forceinline__ uint2 pack4(unsigned short a, unsigned short b,
                                       unsigned short c, unsigned short d) {
  uint2 p;
  p.x = (unsigned)a | ((unsigned)b << 16);
  p.y = (unsigned)c | ((unsigned)d << 16);
  return p;
}

// ---------------- edge_index dtype detection ----------------
__global__ void k_detect(const unsigned* __restrict__ ei, int* __restrict__ flag) {
  __shared__ int nz;
  if (threadIdx.x == 0) nz = 0;
  __syncthreads();
  if (ei[2 * threadIdx.x + 1] != 0u) atomicOr(&nz, 1);
  __syncthreads();
  if (threadIdx.x == 0) *flag = (nz == 0) ? 1 : 0;  // 1 => int64
}

__device__ __forceinline__ int edge_at(const unsigned* __restrict__ ei, int f, int i) {
  return (int)(f ? ei[2 * (size_t)i] : ei[i]);
}

// ---------------- count pass: the ONLY global-atomic kernel ----------------
// rank[e] = old count -> within-segment position (fill needs no atomics).
__global__ void k_cnt(const unsigned* __restrict__ ei, const int* __restrict__ flag,
                      int* __restrict__ cntp, int* __restrict__ rank, int E) {
  int f = *flag;
  int stride = gridDim.x * blockDim.x;
  for (int e = blockIdx.x * blockDim.x + threadIdx.x; e < E; e += stride) {
    int c = edge_at(ei, f, E + e);
    rank[e] = atomicAdd(&cntp[c * CPAD], 1);
  }
}

// ---------------- hierarchical exclusive scan of cntp (padded) ----------------
__global__ __launch_bounds__(256) void k_scanA(const int* __restrict__ cntp,
                                               int* __restrict__ part,
                                               int* __restrict__ bsum, int N) {
  __shared__ int tmp[256];
  int t = threadIdx.x;
  int idx = blockIdx.x * 1024 + t * 4;
  int4 v;
  v.x = idx + 0 < N ? cntp[(size_t)(idx + 0) * CPAD] : 0;
  v.y = idx + 1 < N ? cntp[(size_t)(idx + 1) * CPAD] : 0;
  v.z = idx + 2 < N ? cntp[(size_t)(idx + 2) * CPAD] : 0;
  v.w = idx + 3 < N ? cntp[(size_t)(idx + 3) * CPAD] : 0;
  int s = v.x + v.y + v.z + v.w;
  tmp[t] = s;
  __syncthreads();
#pragma unroll
  for (int d = 1; d < 256; d <<= 1) {
    int u = (t >= d) ? tmp[t - d] : 0;
    __syncthreads();
    tmp[t] += u;
    __syncthreads();
  }
  int excl = tmp[t] - s;
  int4 o;
  o.x = excl;
  o.y = excl + v.x;
  o.z = excl + v.x + v.y;
  o.w = excl + v.x + v.y + v.z;
  if (idx + 3 < N) {
    *(int4*)(part + idx) = o;
  } else {
    if (idx + 0 < N) part[idx + 0] = o.x;
    if (idx + 1 < N) part[idx + 1] = o.y;
    if (idx + 2 < N) part[idx + 2] = o.z;
    if (idx + 3 < N) part[idx + 3] = o.w;
  }
  if (t == 255) bsum[blockIdx.x] = tmp[255];
}

__global__ __launch_bounds__(256) void k_scanB(int* __restrict__ bsum, int nb) {
  __shared__ int tmp[256];
  int t = threadIdx.x;
  int s = (t < nb) ? bsum[t] : 0;
  tmp[t] = s;
  __syncthreads();
#pragma unroll
  for (int d = 1; d < 256; d <<= 1) {
    int u = (t >= d) ? tmp[t - d] : 0;
    __syncthreads();
    tmp[t] += u;
    __syncthreads();
  }
  bsum[t] = tmp[t] - s;
}

__global__ void k_scanC(const int* __restrict__ part, const int* __restrict__ bsum,
                        int* __restrict__ rowptr, int N, int E) {
  int i = blockIdx.x * blockDim.x + threadIdx.x;
  if (i < N) rowptr[i] = part[i] + bsum[i >> 10];
  if (i == 0) rowptr[N] = E;
}

// ---------------- fill: pure scatter, NO atomics ----------------
__global__ void k_fill(const unsigned* __restrict__ ei, const int* __restrict__ flag,
                       const float* __restrict__ ew, const int* __restrict__ rowptr,
                       const int* __restrict__ rank, int* __restrict__ csrc,
                       float* __restrict__ cew, int E) {
  int f = *flag;
  int stride = gridDim.x * blockDim.x;
  for (int e = blockIdx.x * blockDim.x + threadIdx.x; e < E; e += stride) {
    int r = edge_at(ei, f, e);
    int c = edge_at(ei, f, E + e);
    int p = rowptr[c] + rank[e];
    csrc[p] = r;
    cew[p] = ew[e];
  }
}

// ---------------- segmented deg-sum -> dinv (quarter-wave per node) ----------
__global__ void k_degsum(const float* __restrict__ cew, const int* __restrict__ rowptr,
                         float* __restrict__ dinv, int N) {
  int g = blockIdx.x * blockDim.x + threadIdx.x;
  int node = g >> 4, l = g & 15;
  if (node >= N) return;
  int s = rowptr[node], epd = rowptr[node + 1];
  float sum = 0.f;
  for (int p = s + l; p < epd; p += 16) sum += cew[p];
  sum += __shfl_xor(sum, 1);
  sum += __shfl_xor(sum, 2);
  sum += __shfl_xor(sum, 4);
  sum += __shfl_xor(sum, 8);
  if (l == 0) {
    float d = sum + 1.0f;  // self loop; always > 0
    float y = rsqrtf(d);
    y = y * (1.5f - 0.5f * d * y * y);  // Newton: ~1 ulp f32
    dinv[node] = y;
  }
}

// ---------------- bake symmetric norm into CSR weights (in-place) ------------
__global__ void k_scale(const int* __restrict__ csrc, const int* __restrict__ rowptr,
                        const float* __restrict__ dinv, float* __restrict__ cw, int N) {
  int g = blockIdx.x * blockDim.x + threadIdx.x;
  int node = g >> 4, l = g & 15;
  if (node >= N) return;
  float dn = dinv[node];
  int s = rowptr[node], epd = rowptr[node + 1];
  for (int p = s + l; p < epd; p += 16) cw[p] = dinv[csrc[p]] * cw[p] * dn;
}

// ---------------- GEMM1 (split-bf16 MFMA): h = x[M,512] @ W1[128,512]^T --------
__global__ __launch_bounds__(256) void k_gemm1m(const float* __restrict__ x,
                                                const float* __restrict__ W,
                                                __half* __restrict__ h, int M) {
  __shared__ short xh[4][128][8], xl[4][128][8];
  __shared__ short wh[4][128][8], wl[4][128][8];
  const int t = threadIdx.x;
  const int lane = t & 63, w = t >> 6;
  const int wm = (w >> 1) * 64, wn = (w & 1) * 64;
  const int kb = lane >> 4, r16 = lane & 15;
  const int m0 = blockIdx.x * 128;

  float4v acc[4][4];
#pragma unroll
  for (int mi = 0; mi < 4; mi++)
#pragma unroll
    for (int nj = 0; nj < 4; nj++) acc[mi][nj] = (float4v)0.f;

  for (int k0 = 0; k0 < IN_C; k0 += 32) {
#pragma unroll
    for (int i = 0; i < 4; i++) {
      int idx = t + i * 256;
      int row = idx >> 3, kc = idx & 7;
      int gr = m0 + row;
      if (gr >= M) gr = M - 1;
      float4 v = *(const float4*)(x + (size_t)gr * IN_C + k0 + kc * 4);
      unsigned short h0 = f2bf(v.x), h1 = f2bf(v.y), h2 = f2bf(v.z), h3 = f2bf(v.w);
      unsigned short l0 = f2bf(v.x - bf2f(h0)), l1 = f2bf(v.y - bf2f(h1));
      unsigned short l2 = f2bf(v.z - bf2f(h2)), l3 = f2bf(v.w - bf2f(h3));
      int kbw = kc >> 1, s = kc & 1;
      *(uint2*)&xh[kbw][row][s * 4] = pack4(h0, h1, h2, h3);
      *(uint2*)&xl[kbw][row][s * 4] = pack4(l0, l1, l2, l3);
    }
#pragma unroll
    for (int i = 0; i < 4; i++) {
      int idx = t + i * 256;
      int n = idx >> 3, kc = idx & 7;
      float4 v = *(const float4*)(W + (size_t)n * IN_C + k0 + kc * 4);
      unsigned short h0 = f2bf(v.x), h1 = f2bf(v.y), h2 = f2bf(v.z), h3 = f2bf(v.w);
      unsigned short l0 = f2bf(v.x - bf2f(h0)), l1 = f2bf(v.y - bf2f(h1));
      unsigned short l2 = f2bf(v.z - bf2f(h2)), l3 = f2bf(v.w - bf2f(h3));
      int kbw = kc >> 1, s = kc & 1;
      *(uint2*)&wh[kbw][n][s * 4] = pack4(h0, h1, h2, h3);
      *(uint2*)&wl[kbw][n][s * 4] = pack4(l0, l1, l2, l3);
    }
    __syncthreads();

    short8v ah[4], al[4], bh[4], bl[4];
#pragma unroll
    for (int mi = 0; mi < 4; mi++) {
      ah[mi] = *(short8v*)&xh[kb][wm + mi * 16 + r16][0];
      al[mi] = *(short8v*)&xl[kb][wm + mi * 16 + r16][0];
    }
#pragma unroll
    for (int nj = 0; nj < 4; nj++) {
      bh[nj] = *(short8v*)&wh[kb][wn + nj * 16 + r16][0];
      bl[nj] = *(short8v*)&wl[kb][wn + nj * 16 + r16][0];
    }
#pragma unroll
    for (int mi = 0; mi < 4; mi++)
#pragma unroll
      for (int nj = 0; nj < 4; nj++) {
        acc[mi][nj] = __builtin_amdgcn_mfma_f32_16x16x32_bf16(ah[mi], bh[nj], acc[mi][nj], 0, 0, 0);
        acc[mi][nj] = __builtin_amdgcn_mfma_f32_16x16x32_bf16(ah[mi], bl[nj], acc[mi][nj], 0, 0, 0);
        acc[mi][nj] = __builtin_amdgcn_mfma_f32_16x16x32_bf16(al[mi], bh[nj], acc[mi][nj], 0, 0, 0);
      }
    __syncthreads();
  }

#pragma unroll
  for (int mi = 0; mi < 4; mi++)
#pragma unroll
    for (int nj = 0; nj < 4; nj++) {
#pragma unroll
      for (int b = 0; b < 4; b++) {
        int grow = m0 + wm + mi * 16 + (lane >> 4) * 4 + b;
        int gcol = wn + nj * 16 + r16;
        if (grow < M) h[(size_t)grow * HID + gcol] = __float2half(acc[mi][nj][b]);
      }
    }
}

// ---------------- GEMM2 (split-bf16 MFMA): h2 = z[M,128] @ W2[64,128]^T --------
__global__ __launch_bounds__(256) void k_gemm2m(const float* __restrict__ z,
                                                const float* __restrict__ W,
                                                __half* __restrict__ h, int M) {
  __shared__ short zh[4][128][8], zl[4][128][8];
  __shared__ short wh[4][64][8], wl[4][64][8];
  const int t = threadIdx.x;
  const int lane = t & 63, w = t >> 6;
  const int wm = (w >> 1) * 64, wn = (w & 1) * 32;
  const int kb = lane >> 4, r16 = lane & 15;
  const int m0 = blockIdx.x * 128;

  float4v acc[4][2];
#pragma unroll
  for (int mi = 0; mi < 4; mi++)
#pragma unroll
    for (int nj = 0; nj < 2; nj++) acc[mi][nj] = (float4v)0.f;

  for (int k0 = 0; k0 < HID; k0 += 32) {
#pragma unroll
    for (int i = 0; i < 4; i++) {
      int idx = t + i * 256;
      int row = idx >> 3, kc = idx & 7;
      int gr = m0 + row;
      if (gr >= M) gr = M - 1;
      float4 v = *(const float4*)(z + (size_t)gr * HID + k0 + kc * 4);
      unsigned short h0 = f2bf(v.x), h1 = f2bf(v.y), h2 = f2bf(v.z), h3 = f2bf(v.w);
      unsigned short l0 = f2bf(v.x - bf2f(h0)), l1 = f2bf(v.y - bf2f(h1));
      unsigned short l2 = f2bf(v.z - bf2f(h2)), l3 = f2bf(v.w - bf2f(h3));
      int kbw = kc >> 1, s = kc & 1;
      *(uint2*)&zh[kbw][row][s * 4] = pack4(h0, h1, h2, h3);
      *(uint2*)&zl[kbw][row][s * 4] = pack4(l0, l1, l2, l3);
    }
#pragma unroll
    for (int i = 0; i < 2; i++) {
      int idx = t + i * 256;
      int n = idx >> 3, kc = idx & 7;
      float4 v = *(const float4*)(W + (size_t)n * HID + k0 + kc * 4);
      unsigned short h0 = f2bf(v.x), h1 = f2bf(v.y), h2 = f2bf(v.z), h3 = f2bf(v.w);
      unsigned short l0 = f2bf(v.x - bf2f(h0)), l1 = f2bf(v.y - bf2f(h1));
      unsigned short l2 = f2bf(v.z - bf2f(h2)), l3 = f2bf(v.w - bf2f(h3));
      int kbw = kc >> 1, s = kc & 1;
      *(uint2*)&wh[kbw][n][s * 4] = pack4(h0, h1, h2, h3);
      *(uint2*)&wl[kbw][n][s * 4] = pack4(l0, l1, l2, l3);
    }
    __syncthreads();

    short8v ah[4], al[4], bh[2], bl[2];
#pragma unroll
    for (int mi = 0; mi < 4; mi++) {
      ah[mi] = *(short8v*)&zh[kb][wm + mi * 16 + r16][0];
      al[mi] = *(short8v*)&zl[kb][wm + mi * 16 + r16][0];
    }
#pragma unroll
    for (int nj = 0; nj < 2; nj++) {
      bh[nj] = *(short8v*)&wh[kb][wn + nj * 16 + r16][0];
      bl[nj] = *(short8v*)&wl[kb][wn + nj * 16 + r16][0];
    }
#pragma unroll
    for (int mi = 0; mi < 4; mi++)
#pragma unroll
      for (int nj = 0; nj < 2; nj++) {
        acc[mi][nj] = __builtin_amdgcn_mfma_f32_16x16x32_bf16(ah[mi], bh[nj], acc[mi][nj], 0, 0, 0);
        acc[mi][nj] = __builtin_amdgcn_mfma_f32_16x16x32_bf16(ah[mi], bl[nj], acc[mi][nj], 0, 0, 0);
        acc[mi][nj] = __builtin_amdgcn_mfma_f32_16x16x32_bf16(al[mi], bh[nj], acc[mi][nj], 0, 0, 0);
      }
    __syncthreads();
  }

#pragma unroll
  for (int mi = 0; mi < 4; mi++)
#pragma unroll
    for (int nj = 0; nj < 2; nj++) {
#pragma unroll
      for (int b = 0; b < 4; b++) {
        int grow = m0 + wm + mi * 16 + (lane >> 4) * 4 + b;
        int gcol = wn + nj * 16 + r16;
        if (grow < M) h[(size_t)grow * HID2 + gcol] = __float2half(acc[mi][nj][b]);
      }
    }
}

// ---------------- aggregation (pull over CSR, fp16 gather) + bias + PReLU -------
__global__ void k_agg1(const __half* __restrict__ h, const int* __restrict__ rowptr,
                       const int* __restrict__ csrc, const float* __restrict__ cw,
                       const float* __restrict__ dinv, const float* __restrict__ bias,
                       const float* __restrict__ alpha, float* __restrict__ z, int N) {
  int node = blockIdx.x * 4 + (threadIdx.x >> 6);
  int lane = threadIdx.x & 63;
  if (node >= N) return;
  const __half2* hp = (const __half2*)h;
  float2 acc = make_float2(0.f, 0.f);
  int s = rowptr[node];
  int dg = rowptr[node + 1] - s;
  for (int base = 0; base < dg; base += 64) {
    int k = base + lane;
    int msrc = 0;
    float mw = 0.f;
    if (k < dg) {
      msrc = csrc[s + k];
      mw = cw[s + k];
    }
    int cnt = min(64, dg - base);
    for (int j = 0; j < cnt; j++) {
      int src = __shfl(msrc, j);
      float wv = __shfl(mw, j);
      float2 v = __half22float2(hp[(size_t)src * 64 + lane]);
      acc.x += wv * v.x;
      acc.y += wv * v.y;
    }
  }
  float di = dinv[node];
  float sw = di * di;
  float2 v = __half22float2(hp[(size_t)node * 64 + lane]);
  acc.x += sw * v.x;
  acc.y += sw * v.y;
  acc.x += bias[lane * 2];
  acc.y += bias[lane * 2 + 1];
  float a0 = alpha[lane * 2], a1 = alpha[lane * 2 + 1];
  acc.x = acc.x >= 0.f ? acc.x : a0 * acc.x;
  acc.y = acc.y >= 0.f ? acc.y : a1 * acc.y;
  ((float2*)z)[(size_t)node * 64 + lane] = acc;
}

__global__ void k_agg2(const __half* __restrict__ h, const int* __restrict__ rowptr,
                       const int* __restrict__ csrc, const float* __restrict__ cw,
                       const float* __restrict__ dinv, const float* __restrict__ bias,
                       const float* __restrict__ alpha, float* __restrict__ out, int N) {
  int node = blockIdx.x * 4 + (threadIdx.x >> 6);
  int lane = threadIdx.x & 63;
  if (node >= N) return;
  float acc = 0.f;
  int s = rowptr[node];
  int dg = rowptr[node + 1] - s;
  for (int base = 0; base < dg; base += 64) {
    int k = base + lane;
    int msrc = 0;
    float mw = 0.f;
    if (k < dg) {
      msrc = csrc[s + k];
      mw = cw[s + k];
    }
    int cnt = min(64, dg - base);
    for (int j = 0; j < cnt; j++) {
      int src = __shfl(msrc, j);
      float wv = __shfl(mw, j);
      acc += wv * __half2float(h[(size_t)src * HID2 + lane]);
    }
  }
  float di = dinv[node];
  acc += di * di * __half2float(h[(size_t)node * HID2 + lane]);
  acc += bias[lane];
  float a = alpha[lane];
  acc = acc >= 0.f ? acc : a * acc;
  out[(size_t)node * HID2 + lane] = acc;
}

extern "C" void kernel_launch(void* const* d_in, const int* in_sizes, int n_in,
                              void* d_out, int out_size, void* d_ws, size_t ws_size,
                              hipStream_t stream) {
  const float* x = (const float*)d_in[0];
  const unsigned* ei = (const unsigned*)d_in[1];
  const float* ew = (const float*)d_in[2];
  const float* W1 = (const float*)d_in[3];
  const float* b1 = (const float*)d_in[4];
  const float* a1 = (const float*)d_in[5];
  const float* W2 = (const float*)d_in[6];
  const float* b2 = (const float*)d_in[7];
  const float* a2 = (const float*)d_in[8];
  float* out = (float*)d_out;

  const int N = in_sizes[0] / IN_C;
  const int E = in_sizes[2];
  const int NB = (N + 1023) / 1024;

  char* w = (char*)d_ws;
  auto alloc = [&](size_t bytes) -> void* {
    void* p = (void*)w;
    w += (bytes + 255) / 256 * 256;
    return p;
  };
  int* flag = (int*)alloc(4);
  int* cntp = (int*)alloc((size_t)N * CPAD * 4);  // padded counters, 128B/node
  int* rank = (int*)alloc((size_t)E * 4);
  float* dinv = (float*)alloc((size_t)N * 4);
  int* rowptr = (int*)alloc((size_t)(N + 1) * 4);
  int* part = (int*)alloc((size_t)N * 4);
  int* bsum = (int*)alloc(256 * 4);
  int* csrc = (int*)alloc((size_t)E * 4);
  float* cw = (float*)alloc((size_t)E * 4);  // ew then normalized in-place
  __half* h1 = (__half*)alloc((size_t)N * HID * 2);
  float* z1 = (float*)alloc((size_t)N * HID * 4);
  __half* h2 = (__half*)alloc((size_t)N * HID2 * 2);

  hipMemsetAsync(cntp, 0, (size_t)N * CPAD * 4, stream);

  k_detect<<<1, 256, 0, stream>>>(ei, flag);
  k_cnt<<<1024, 256, 0, stream>>>(ei, flag, cntp, rank, E);
  k_scanA<<<NB, 256, 0, stream>>>(cntp, part, bsum, N);
  k_scanB<<<1, 256, 0, stream>>>(bsum, NB);
  k_scanC<<<(N + 255) / 256, 256, 0, stream>>>(part, bsum, rowptr, N, E);
  k_fill<<<1024, 256, 0, stream>>>(ei, flag, ew, rowptr, rank, csrc, cw, E);
  k_degsum<<<(N * 16 + 255) / 256, 256, 0, stream>>>(cw, rowptr, dinv, N);
  k_scale<<<(N * 16 + 255) / 256, 256, 0, stream>>>(csrc, rowptr, dinv, cw, N);

  k_gemm1m<<<(N + 127) / 128, 256, 0, stream>>>(x, W1, h1, N);
  k_agg1<<<(N + 3) / 4, 256, 0, stream>>>(h1, rowptr, csrc, cw, dinv, b1, a1, z1, N);
  k_gemm2m<<<(N + 127) / 128, 256, 0, stream>>>(z1, W2, h2, N);
  k_agg2<<<(N + 3) / 4, 256, 0, stream>>>(h2, rowptr, csrc, cw, dinv, b2, a2, out, N);
}

// Round 9
// 374.656 us; speedup vs baseline: 1.7972x; 1.0491x over previous
//
#include <hip/hip_runtime.h>
#include <hip/hip_fp16.h>

#define IN_C 512
#define HID  128
#define HID2 64
#define CPAD 32  // counter padding: 32 ints = 128B per node

typedef __attribute__((ext_vector_type(8))) short short8v;
typedef __attribute__((ext_vector_type(4))) float float4v;

__device__ __forceinline__ unsigned short f2bf(float f) {
  unsigned u = __float_as_uint(f);
  unsigned r = u + 0x7FFF + ((u >> 16) & 1);  // RNE
  return (unsigned short)(r >> 16);
}
__device__ __forceinline__ float bf2f(unsigned short h) {
  return __uint_as_float((unsigned)h << 16);
}
__device__ __forceinline__ uint2 pack4(unsigned short a, unsigned short b,
                                       unsigned short c, unsigned short d) {
  uint2 p;
  p.x = (unsigned)a | ((unsigned)b << 16);
  p.y = (unsigned)c | ((unsigned)d << 16);
  return p;
}
__device__ __forceinline__ void split4(float4 v, uint2& hi, uint2& lo) {
  unsigned short h0 = f2bf(v.x), h1 = f2bf(v.y), h2 = f2bf(v.z), h3 = f2bf(v.w);
  unsigned short l0 = f2bf(v.x - bf2f(h0)), l1 = f2bf(v.y - bf2f(h1));
  unsigned short l2 = f2bf(v.z - bf2f(h2)), l3 = f2bf(v.w - bf2f(h3));
  hi = pack4(h0, h1, h2, h3);
  lo = pack4(l0, l1, l2, l3);
}

// ---------------- edge_index dtype detection ----------------
__global__ void k_detect(const unsigned* __restrict__ ei, int* __restrict__ flag) {
  __shared__ int nz;
  if (threadIdx.x == 0) nz = 0;
  __syncthreads();
  if (ei[2 * threadIdx.x + 1] != 0u) atomicOr(&nz, 1);
  __syncthreads();
  if (threadIdx.x == 0) *flag = (nz == 0) ? 1 : 0;  // 1 => int64
}

__device__ __forceinline__ int edge_at(const unsigned* __restrict__ ei, int f, int i) {
  return (int)(f ? ei[2 * (size_t)i] : ei[i]);
}

// ---------------- pre-split W1/W2 into bf16 hi/lo (once, not per block) -------
// layout: w1h[kk][n][8] with kk = k/8  (k = kk*8+j), same for lo / W2.
__global__ void k_wsplit(const float* __restrict__ W1, const float* __restrict__ W2,
                         short* __restrict__ w1h, short* __restrict__ w1l,
                         short* __restrict__ w2h, short* __restrict__ w2l) {
  int tid = blockIdx.x * blockDim.x + threadIdx.x;
  if (tid < 128 * (IN_C / 4)) {  // W1: n=tid/(512/4), k=4*(tid%128)
    int n = tid >> 7, k = (tid & 127) * 4;
    float4 v = *(const float4*)(W1 + (size_t)n * IN_C + k);
    uint2 hi, lo;
    split4(v, hi, lo);
    size_t base = (((size_t)(k >> 3)) * 128 + n) * 8 + (k & 7);
    *(uint2*)(w1h + base) = hi;
    *(uint2*)(w1l + base) = lo;
  } else if (tid < 128 * (IN_C / 4) + 64 * (HID / 4)) {  // W2
    int t = tid - 128 * (IN_C / 4);
    int n = t >> 5, k = (t & 31) * 4;
    float4 v = *(const float4*)(W2 + (size_t)n * HID + k);
    uint2 hi, lo;
    split4(v, hi, lo);
    size_t base = (((size_t)(k >> 3)) * 64 + n) * 8 + (k & 7);
    *(uint2*)(w2h + base) = hi;
    *(uint2*)(w2l + base) = lo;
  }
}

// ---------------- count pass: the ONLY global-atomic kernel ----------------
__global__ void k_cnt(const unsigned* __restrict__ ei, const int* __restrict__ flag,
                      int* __restrict__ cntp, int* __restrict__ rank, int E) {
  int f = *flag;
  int stride = gridDim.x * blockDim.x * 2;
  for (int e = (blockIdx.x * blockDim.x + threadIdx.x) * 2; e < E; e += stride) {
    int c0, c1 = -1;
    if (f) {
      if (e + 1 < E) {
        uint4 v = *(const uint4*)(ei + 2 * (size_t)(E + e));
        c0 = (int)v.x;
        c1 = (int)v.z;
      } else {
        c0 = (int)ei[2 * (size_t)(E + e)];
      }
    } else {
      if (e + 1 < E) {
        uint2 v = *(const uint2*)(ei + (size_t)E + e);
        c0 = (int)v.x;
        c1 = (int)v.y;
      } else {
        c0 = (int)ei[(size_t)E + e];
      }
    }
    rank[e] = atomicAdd(&cntp[c0 * CPAD], 1);
    if (c1 >= 0) rank[e + 1] = atomicAdd(&cntp[c1 * CPAD], 1);
  }
}

// ---------------- hierarchical exclusive scan of cntp (padded) ----------------
__global__ __launch_bounds__(256) void k_scanA(const int* __restrict__ cntp,
                                               int* __restrict__ part,
                                               int* __restrict__ bsum, int N) {
  __shared__ int tmp[256];
  int t = threadIdx.x;
  int idx = blockIdx.x * 1024 + t * 4;
  int4 v;
  v.x = idx + 0 < N ? cntp[(size_t)(idx + 0) * CPAD] : 0;
  v.y = idx + 1 < N ? cntp[(size_t)(idx + 1) * CPAD] : 0;
  v.z = idx + 2 < N ? cntp[(size_t)(idx + 2) * CPAD] : 0;
  v.w = idx + 3 < N ? cntp[(size_t)(idx + 3) * CPAD] : 0;
  int s = v.x + v.y + v.z + v.w;
  tmp[t] = s;
  __syncthreads();
#pragma unroll
  for (int d = 1; d < 256; d <<= 1) {
    int u = (t >= d) ? tmp[t - d] : 0;
    __syncthreads();
    tmp[t] += u;
    __syncthreads();
  }
  int excl = tmp[t] - s;
  int4 o;
  o.x = excl;
  o.y = excl + v.x;
  o.z = excl + v.x + v.y;
  o.w = excl + v.x + v.y + v.z;
  if (idx + 3 < N) {
    *(int4*)(part + idx) = o;
  } else {
    if (idx + 0 < N) part[idx + 0] = o.x;
    if (idx + 1 < N) part[idx + 1] = o.y;
    if (idx + 2 < N) part[idx + 2] = o.z;
    if (idx + 3 < N) part[idx + 3] = o.w;
  }
  if (t == 255) bsum[blockIdx.x] = tmp[255];
}

__global__ __launch_bounds__(256) void k_scanB(int* __restrict__ bsum, int nb) {
  __shared__ int tmp[256];
  int t = threadIdx.x;
  int s = (t < nb) ? bsum[t] : 0;
  tmp[t] = s;
  __syncthreads();
#pragma unroll
  for (int d = 1; d < 256; d <<= 1) {
    int u = (t >= d) ? tmp[t - d] : 0;
    __syncthreads();
    tmp[t] += u;
    __syncthreads();
  }
  bsum[t] = tmp[t] - s;
}

__global__ void k_scanC(const int* __restrict__ part, const int* __restrict__ bsum,
                        int* __restrict__ rowptr, int N, int E) {
  int i = blockIdx.x * blockDim.x + threadIdx.x;
  if (i < N) rowptr[i] = part[i] + bsum[i >> 10];
  if (i == 0) rowptr[N] = E;
}

// ---------------- fill: pure scatter, NO atomics; packed (src, w) ------------
__global__ void k_fill(const unsigned* __restrict__ ei, const int* __restrict__ flag,
                       const float* __restrict__ ew, const int* __restrict__ rowptr,
                       const int* __restrict__ rank, uint2* __restrict__ ep, int E) {
  int f = *flag;
  int stride = gridDim.x * blockDim.x;
  for (int e = blockIdx.x * blockDim.x + threadIdx.x; e < E; e += stride) {
    int r = edge_at(ei, f, e);
    int c = edge_at(ei, f, E + e);
    int p = rowptr[c] + rank[e];
    uint2 m;
    m.x = (unsigned)r;
    m.y = __float_as_uint(ew[e]);
    ep[p] = m;
  }
}

// ---------------- segmented deg-sum -> dinv (quarter-wave per node) ----------
__global__ void k_degsum(const uint2* __restrict__ ep, const int* __restrict__ rowptr,
                         float* __restrict__ dinv, int N) {
  int g = blockIdx.x * blockDim.x + threadIdx.x;
  int node = g >> 4, l = g & 15;
  if (node >= N) return;
  int s = rowptr[node], epd = rowptr[node + 1];
  float sum = 0.f;
  for (int p = s + l; p < epd; p += 16) sum += __uint_as_float(ep[p].y);
  sum += __shfl_xor(sum, 1);
  sum += __shfl_xor(sum, 2);
  sum += __shfl_xor(sum, 4);
  sum += __shfl_xor(sum, 8);
  if (l == 0) {
    float d = sum + 1.0f;  // self loop; always > 0
    float y = rsqrtf(d);
    y = y * (1.5f - 0.5f * d * y * y);  // Newton: ~1 ulp f32
    dinv[node] = y;
  }
}

// ---------------- bake symmetric norm into packed weights (in-place) ----------
__global__ void k_scale(uint2* __restrict__ ep, const int* __restrict__ rowptr,
                        const float* __restrict__ dinv, int N) {
  int g = blockIdx.x * blockDim.x + threadIdx.x;
  int node = g >> 4, l = g & 15;
  if (node >= N) return;
  float dn = dinv[node];
  int s = rowptr[node], epd = rowptr[node + 1];
  for (int p = s + l; p < epd; p += 16) {
    uint2 m = ep[p];
    ep[p].y = __float_as_uint(dinv[m.x] * __uint_as_float(m.y) * dn);
  }
}

// ---------------- GEMM1 (split-bf16 MFMA): h = x[M,512] @ W1[128,512]^T --------
__global__ __launch_bounds__(256) void k_gemm1m(const float* __restrict__ x,
                                                const short* __restrict__ w1h,
                                                const short* __restrict__ w1l,
                                                __half* __restrict__ h, int M) {
  __shared__ short xh[4][128][8], xl[4][128][8];
  __shared__ short wh[4][128][8], wl[4][128][8];
  const int t = threadIdx.x;
  const int lane = t & 63, w = t >> 6;
  const int wm = (w >> 1) * 64, wn = (w & 1) * 64;
  const int kb = lane >> 4, r16 = lane & 15;
  const int m0 = blockIdx.x * 128;

  float4v acc[4][4];
#pragma unroll
  for (int mi = 0; mi < 4; mi++)
#pragma unroll
    for (int nj = 0; nj < 4; nj++) acc[mi][nj] = (float4v)0.f;

  for (int k0 = 0; k0 < IN_C; k0 += 32) {
    // stage x tile: 128 rows x 32 k = 1024 float4, converted inline
#pragma unroll
    for (int i = 0; i < 4; i++) {
      int idx = t + i * 256;
      int row = idx >> 3, kc = idx & 7;
      int gr = m0 + row;
      if (gr >= M) gr = M - 1;
      float4 v = *(const float4*)(x + (size_t)gr * IN_C + k0 + kc * 4);
      uint2 hi, lo;
      split4(v, hi, lo);
      int kbw = kc >> 1, s = kc & 1;
      *(uint2*)&xh[kbw][row][s * 4] = hi;
      *(uint2*)&xl[kbw][row][s * 4] = lo;
    }
    // stage W tile from pre-split arrays: 512 short8 chunks x2 (hi,lo)
#pragma unroll
    for (int i = 0; i < 2; i++) {
      int idx = t + i * 256;
      int kb2 = idx >> 7, n = idx & 127;
      size_t gbase = (((size_t)(k0 >> 3) + kb2) * 128 + n) * 8;
      *(short8v*)&wh[kb2][n][0] = *(const short8v*)(w1h + gbase);
      *(short8v*)&wl[kb2][n][0] = *(const short8v*)(w1l + gbase);
    }
    __syncthreads();

    short8v ah[4], al[4], bh[4], bl[4];
#pragma unroll
    for (int mi = 0; mi < 4; mi++) {
      ah[mi] = *(short8v*)&xh[kb][wm + mi * 16 + r16][0];
      al[mi] = *(short8v*)&xl[kb][wm + mi * 16 + r16][0];
    }
#pragma unroll
    for (int nj = 0; nj < 4; nj++) {
      bh[nj] = *(short8v*)&wh[kb][wn + nj * 16 + r16][0];
      bl[nj] = *(short8v*)&wl[kb][wn + nj * 16 + r16][0];
    }
#pragma unroll
    for (int mi = 0; mi < 4; mi++)
#pragma unroll
      for (int nj = 0; nj < 4; nj++) {
        acc[mi][nj] = __builtin_amdgcn_mfma_f32_16x16x32_bf16(ah[mi], bh[nj], acc[mi][nj], 0, 0, 0);
        acc[mi][nj] = __builtin_amdgcn_mfma_f32_16x16x32_bf16(ah[mi], bl[nj], acc[mi][nj], 0, 0, 0);
        acc[mi][nj] = __builtin_amdgcn_mfma_f32_16x16x32_bf16(al[mi], bh[nj], acc[mi][nj], 0, 0, 0);
      }
    __syncthreads();
  }

#pragma unroll
  for (int mi = 0; mi < 4; mi++)
#pragma unroll
    for (int nj = 0; nj < 4; nj++) {
#pragma unroll
      for (int b = 0; b < 4; b++) {
        int grow = m0 + wm + mi * 16 + (lane >> 4) * 4 + b;
        int gcol = wn + nj * 16 + r16;
        if (grow < M) h[(size_t)grow * HID + gcol] = __float2half(acc[mi][nj][b]);
      }
    }
}

// ---------------- GEMM2 (split-bf16 MFMA): h2 = z[M,128] @ W2[64,128]^T --------
__global__ __launch_bounds__(256) void k_gemm2m(const float* __restrict__ z,
                                                const short* __restrict__ w2h,
                                                const short* __restrict__ w2l,
                                                __half* __restrict__ h, int M) {
  __shared__ short zh[4][128][8], zl[4][128][8];
  __shared__ short wh[4][64][8], wl[4][64][8];
  const int t = threadIdx.x;
  const int lane = t & 63, w = t >> 6;
  const int wm = (w >> 1) * 64, wn = (w & 1) * 32;
  const int kb = lane >> 4, r16 = lane & 15;
  const int m0 = blockIdx.x * 128;

  float4v acc[4][2];
#pragma unroll
  for (int mi = 0; mi < 4; mi++)
#pragma unroll
    for (int nj = 0; nj < 2; nj++) acc[mi][nj] = (float4v)0.f;

  for (int k0 = 0; k0 < HID; k0 += 32) {
#pragma unroll
    for (int i = 0; i < 4; i++) {
      int idx = t + i * 256;
      int row = idx >> 3, kc = idx & 7;
      int gr = m0 + row;
      if (gr >= M) gr = M - 1;
      float4 v = *(const float4*)(z + (size_t)gr * HID + k0 + kc * 4);
      uint2 hi, lo;
      split4(v, hi, lo);
      int kbw = kc >> 1, s = kc & 1;
      *(uint2*)&zh[kbw][row][s * 4] = hi;
      *(uint2*)&zl[kbw][row][s * 4] = lo;
    }
    {  // W2 tile: 256 short8 chunks x2 from pre-split
      int kb2 = t >> 6, n = t & 63;
      size_t gbase = (((size_t)(k0 >> 3) + kb2) * 64 + n) * 8;
      *(short8v*)&wh[kb2][n][0] = *(const short8v*)(w2h + gbase);
      *(short8v*)&wl[kb2][n][0] = *(const short8v*)(w2l + gbase);
    }
    __syncthreads();

    short8v ah[4], al[4], bh[2], bl[2];
#pragma unroll
    for (int mi = 0; mi < 4; mi++) {
      ah[mi] = *(short8v*)&zh[kb][wm + mi * 16 + r16][0];
      al[mi] = *(short8v*)&zl[kb][wm + mi * 16 + r16][0];
    }
#pragma unroll
    for (int nj = 0; nj < 2; nj++) {
      bh[nj] = *(short8v*)&wh[kb][wn + nj * 16 + r16][0];
      bl[nj] = *(short8v*)&wl[kb][wn + nj * 16 + r16][0];
    }
#pragma unroll
    for (int mi = 0; mi < 4; mi++)
#pragma unroll
      for (int nj = 0; nj < 2; nj++) {
        acc[mi][nj] = __builtin_amdgcn_mfma_f32_16x16x32_bf16(ah[mi], bh[nj], acc[mi][nj], 0, 0, 0);
        acc[mi][nj] = __builtin_amdgcn_mfma_f32_16x16x32_bf16(ah[mi], bl[nj], acc[mi][nj], 0, 0, 0);
        acc[mi][nj] = __builtin_amdgcn_mfma_f32_16x16x32_bf16(al[mi], bh[nj], acc[mi][nj], 0, 0, 0);
      }
    __syncthreads();
  }

#pragma unroll
  for (int mi = 0; mi < 4; mi++)
#pragma unroll
    for (int nj = 0; nj < 2; nj++) {
#pragma unroll
      for (int b = 0; b < 4; b++) {
        int grow = m0 + wm + mi * 16 + (lane >> 4) * 4 + b;
        int gcol = wn + nj * 16 + r16;
        if (grow < M) h[(size_t)grow * HID2 + gcol] = __float2half(acc[mi][nj][b]);
      }
    }
}

// ---------------- aggregation (pull over CSR, fp16 gather) + bias + PReLU -------
__global__ void k_agg1(const __half* __restrict__ h, const int* __restrict__ rowptr,
                       const uint2* __restrict__ ep, const float* __restrict__ dinv,
                       const float* __restrict__ bias, const float* __restrict__ alpha,
                       float* __restrict__ z, int N) {
  int node = blockIdx.x * 4 + (threadIdx.x >> 6);
  int lane = threadIdx.x & 63;
  if (node >= N) return;
  const __half2* hp = (const __half2*)h;
  float2 acc = make_float2(0.f, 0.f);
  int s = rowptr[node];
  int dg = rowptr[node + 1] - s;
  for (int base = 0; base < dg; base += 64) {
    int k = base + lane;
    uint2 m = make_uint2(0u, 0u);
    if (k < dg) m = ep[s + k];
    int cnt = min(64, dg - base);
#pragma unroll 4
    for (int j = 0; j < cnt; j++) {
      int src = __shfl((int)m.x, j);
      float wv = __shfl(__uint_as_float(m.y), j);
      float2 v = __half22float2(hp[(size_t)src * 64 + lane]);
      acc.x += wv * v.x;
      acc.y += wv * v.y;
    }
  }
  float di = dinv[node];
  float sw = di * di;
  float2 v = __half22float2(hp[(size_t)node * 64 + lane]);
  acc.x += sw * v.x;
  acc.y += sw * v.y;
  acc.x += bias[lane * 2];
  acc.y += bias[lane * 2 + 1];
  float a0 = alpha[lane * 2], a1 = alpha[lane * 2 + 1];
  acc.x = acc.x >= 0.f ? acc.x : a0 * acc.x;
  acc.y = acc.y >= 0.f ? acc.y : a1 * acc.y;
  ((float2*)z)[(size_t)node * 64 + lane] = acc;
}

__global__ void k_agg2(const __half* __restrict__ h, const int* __restrict__ rowptr,
                       const uint2* __restrict__ ep, const float* __restrict__ dinv,
                       const float* __restrict__ bias, const float* __restrict__ alpha,
                       float* __restrict__ out, int N) {
  int node = blockIdx.x * 4 + (threadIdx.x >> 6);
  int lane = threadIdx.x & 63;
  if (node >= N) return;
  float acc = 0.f;
  int s = rowptr[node];
  int dg = rowptr[node + 1] - s;
  for (int base = 0; base < dg; base += 64) {
    int k = base + lane;
    uint2 m = make_uint2(0u, 0u);
    if (k < dg) m = ep[s + k];
    int cnt = min(64, dg - base);
#pragma unroll 4
    for (int j = 0; j < cnt; j++) {
      int src = __shfl((int)m.x, j);
      float wv = __shfl(__uint_as_float(m.y), j);
      acc += wv * __half2float(h[(size_t)src * HID2 + lane]);
    }
  }
  float di = dinv[node];
  acc += di * di * __half2float(h[(size_t)node * HID2 + lane]);
  acc += bias[lane];
  float a = alpha[lane];
  acc = acc >= 0.f ? acc : a * acc;
  out[(size_t)node * HID2 + lane] = acc;
}

extern "C" void kernel_launch(void* const* d_in, const int* in_sizes, int n_in,
                              void* d_out, int out_size, void* d_ws, size_t ws_size,
                              hipStream_t stream) {
  const float* x = (const float*)d_in[0];
  const unsigned* ei = (const unsigned*)d_in[1];
  const float* ew = (const float*)d_in[2];
  const float* W1 = (const float*)d_in[3];
  const float* b1 = (const float*)d_in[4];
  const float* a1 = (const float*)d_in[5];
  const float* W2 = (const float*)d_in[6];
  const float* b2 = (const float*)d_in[7];
  const float* a2 = (const float*)d_in[8];
  float* out = (float*)d_out;

  const int N = in_sizes[0] / IN_C;
  const int E = in_sizes[2];
  const int NB = (N + 1023) / 1024;

  char* w = (char*)d_ws;
  auto alloc = [&](size_t bytes) -> void* {
    void* p = (void*)w;
    w += (bytes + 255) / 256 * 256;
    return p;
  };
  int* flag = (int*)alloc(4);
  int* cntp = (int*)alloc((size_t)N * CPAD * 4);
  int* rank = (int*)alloc((size_t)E * 4);
  float* dinv = (float*)alloc((size_t)N * 4);
  int* rowptr = (int*)alloc((size_t)(N + 1) * 4);
  int* part = (int*)alloc((size_t)N * 4);
  int* bsum = (int*)alloc(256 * 4);
  uint2* ep = (uint2*)alloc((size_t)E * 8);  // packed (src, w)
  short* w1h = (short*)alloc((size_t)HID * IN_C * 2);
  short* w1l = (short*)alloc((size_t)HID * IN_C * 2);
  short* w2h = (short*)alloc((size_t)HID2 * HID * 2);
  short* w2l = (short*)alloc((size_t)HID2 * HID * 2);
  __half* h1 = (__half*)alloc((size_t)N * HID * 2);
  float* z1 = (float*)alloc((size_t)N * HID * 4);
  __half* h2 = (__half*)alloc((size_t)N * HID2 * 2);

  hipMemsetAsync(cntp, 0, (size_t)N * CPAD * 4, stream);

  k_detect<<<1, 256, 0, stream>>>(ei, flag);
  k_wsplit<<<(128 * (IN_C / 4) + 64 * (HID / 4) + 255) / 256, 256, 0, stream>>>(
      W1, W2, w1h, w1l, w2h, w2l);
  k_cnt<<<1024, 256, 0, stream>>>(ei, flag, cntp, rank, E);
  k_scanA<<<NB, 256, 0, stream>>>(cntp, part, bsum, N);
  k_scanB<<<1, 256, 0, stream>>>(bsum, NB);
  k_scanC<<<(N + 255) / 256, 256, 0, stream>>>(part, bsum, rowptr, N, E);
  k_fill<<<1024, 256, 0, stream>>>(ei, flag, ew, rowptr, rank, ep, E);
  k_degsum<<<(N * 16 + 255) / 256, 256, 0, stream>>>(ep, rowptr, dinv, N);
  k_scale<<<(N * 16 + 255) / 256, 256, 0, stream>>>(ep, rowptr, dinv, N);

  k_gemm1m<<<(N + 127) / 128, 256, 0, stream>>>(x, w1h, w1l, h1, N);
  k_agg1<<<(N + 3) / 4, 256, 0, stream>>>(h1, rowptr, ep, dinv, b1, a1, z1, N);
  k_gemm2m<<<(N + 127) / 128, 256, 0, stream>>>(z1, w2h, w2l, h2, N);
  k_agg2<<<(N + 3) / 4, 256, 0, stream>>>(h2, rowptr, ep, dinv, b2, a2, out, N);
}